// Round 9
// baseline (169.993 us; speedup 1.0000x reference)
//
#include <hip/hip_runtime.h>

typedef unsigned short u16;
typedef unsigned int u32;
typedef __bf16 bf16x8 __attribute__((ext_vector_type(8)));
typedef __bf16 bf16x2 __attribute__((ext_vector_type(2)));
typedef float f32x4 __attribute__((ext_vector_type(4)));
typedef float f32x2 __attribute__((ext_vector_type(2)));
typedef u32 u32x4 __attribute__((ext_vector_type(4)));
typedef u32 u32x2 __attribute__((ext_vector_type(2)));
typedef short s16x4 __attribute__((ext_vector_type(4)));

#define DEVI __device__ __forceinline__

#if defined(__has_builtin)
#if __has_builtin(__builtin_amdgcn_exp2f)
#define EXP2F(x) __builtin_amdgcn_exp2f(x)
#endif
#endif
#ifndef EXP2F
#define EXP2F(x) exp2f(x)
#endif

#define MFMA16(a, b, c) __builtin_amdgcn_mfma_f32_16x16x32_bf16(a, b, c, 0, 0, 0)
#define MFMA1K(a, b, c) __builtin_amdgcn_mfma_f32_16x16x16bf16_1k(a, b, c, 0, 0, 0)

typedef __attribute__((address_space(1))) u32 gu32;
typedef __attribute__((address_space(3))) u32 lu32;
DEVI void gll16(const u16* g, u16* l) {
    __builtin_amdgcn_global_load_lds((const gu32*)g, (lu32*)l, 16, 0, 0);
}
#define WAIT_VM0() __builtin_amdgcn_s_waitcnt(0x0f70)  // vmcnt(0) only

DEVI u16 f2bf(float f) {
    u32 u = __builtin_bit_cast(u32, f);
    u = (u + 0x7FFFu + ((u >> 16) & 1u)) >> 16;
    return (u16)u;
}
DEVI float bf2f(u16 h) {
    u32 u = ((u32)h) << 16;
    return __builtin_bit_cast(float, u);
}
DEVI float bfhi(u32 u) { return __builtin_bit_cast(float, u & 0xFFFF0000u); }
DEVI float bflo(u32 u) { return __builtin_bit_cast(float, u << 16); }
DEVI bf16x8 bc8(u32x4 u) { return __builtin_bit_cast(bf16x8, u); }
DEVI u32 pack2(float a, float b) {
    f32x2 v = {a, b};
    bf16x2 h = __builtin_convertvector(v, bf16x2);
    return __builtin_bit_cast(u32, h);
}

// q scale: dh^-0.5 * log2(e)  (bakes natural-exp into exp2)
#define QSCALE 0.18033688011112042f

// ---------------------------------------------------------------------------
// K0: fused prep. Blocks [0,512): transpose+cast x -> xt[b][p][c] bf16.
//     Blocks [512,768): cast weights + rel tables (rel zero-padded to 128 rows).
__global__ __launch_bounds__(256) void k_prep(const float* __restrict__ x,
                                              const float* __restrict__ wq,
                                              const float* __restrict__ wo,
                                              const float* __restrict__ relh,
                                              const float* __restrict__ relw,
                                              u16* __restrict__ xt, u16* __restrict__ wqb,
                                              u16* __restrict__ wob, u16* __restrict__ relhb,
                                              u16* __restrict__ relwb) {
    int bid = blockIdx.x;
    int t = threadIdx.x;
    if (bid < 512) {
        int pm = bid & 63, cm = (bid >> 6) & 3, b = bid >> 8;
        int p0 = pm * 64, c0 = cm * 64;
        __shared__ float tile[64][65];
#pragma unroll
        for (int it = 0; it < 16; ++it) {
            int idx = it * 256 + t;
            int cl = idx >> 6, pl = idx & 63;
            tile[cl][pl] = x[((size_t)(b * 256 + c0 + cl)) * 4096 + p0 + pl];
        }
        __syncthreads();
#pragma unroll
        for (int it = 0; it < 16; ++it) {
            int idx = it * 256 + t;
            int pl = idx >> 6, cl = idx & 63;
            xt[((size_t)(b * 4096 + p0 + pl)) * 256 + c0 + cl] = f2bf(tile[cl][pl]);
        }
    } else {
        int i0 = (bid - 512) * 256 + t;  // 65536 stride
#pragma unroll
        for (int i = i0; i < 196608; i += 65536) wqb[i] = f2bf(wq[i]);
        if (i0 < 65536) wob[i0] = f2bf(wo[i0]);
        if (i0 < 8192) {
            relhb[i0] = (i0 < 8128) ? f2bf(relh[i0]) : (u16)0;
            relwb[i0] = (i0 < 8128) ? f2bf(relw[i0]) : (u16)0;
        }
    }
}

// ---------------------------------------------------------------------------
// K1: QKV projection GEMM + fused rel-bias tables (B-tile staged via gll, mod-32 swizzle).
// Height table stored TRANSPOSED: HabsT[bh][jh][p].
__global__ __launch_bounds__(256) void k_qkv(const u16* __restrict__ xt, const u16* __restrict__ wqb,
                                             const u16* __restrict__ relwb,
                                             const u16* __restrict__ relhb,
                                             u16* __restrict__ q, u16* __restrict__ k,
                                             u16* __restrict__ vt, u16* __restrict__ Wabs,
                                             u16* __restrict__ HabsT) {
    int pm = blockIdx.x, on = blockIdx.y, b = blockIdx.z;
    int p0 = pm * 64, o0 = on * 64;
    __shared__ __align__(16) u16 Sm[64 * 256];  // 32 KB B-tile; later T[64*72]+Ls[128*72]
    int t = threadIdx.x;
    int wv = t >> 6, l = t & 63, quad = l >> 4, li = l & 15;

    u32x4 areg[8];
    const u32x4* arow = (const u32x4*)(xt + ((size_t)(b * 4096 + p0 + wv * 16 + li)) * 256);
#pragma unroll
    for (int kc = 0; kc < 8; ++kc) areg[kc] = arow[kc * 4 + quad];

    {
        int pc = l & 31;
#pragma unroll
        for (int i = 0; i < 8; ++i) {
            int r = wv * 16 + i * 2 + (l >> 5);
            gll16(wqb + (size_t)(o0 + r) * 256 + ((pc + r) & 31) * 8,
                  Sm + (wv * 16 + i * 2) * 256);
        }
    }
    WAIT_VM0();
    __syncthreads();

    f32x4 acc[4] = {{0, 0, 0, 0}, {0, 0, 0, 0}, {0, 0, 0, 0}, {0, 0, 0, 0}};
#pragma unroll
    for (int kc = 0; kc < 8; ++kc) {
        bf16x8 a = bc8(areg[kc]);
#pragma unroll
        for (int ct = 0; ct < 4; ++ct) {
            bf16x8 bb = bc8(*(const u32x4*)(Sm + (ct * 16 + li) * 256 +
                                            (((kc * 4 + quad) - (ct * 16 + li)) & 31) * 8));
            acc[ct] = MFMA16(a, bb, acc[ct]);
        }
    }

    int tensor = on >> 2, head = on & 3;
    if (tensor == 2) {
        __syncthreads();
        u16* T = Sm;  // [64 d][72 p]
#pragma unroll
        for (int ct = 0; ct < 4; ++ct)
#pragma unroll
            for (int r = 0; r < 4; ++r)
                T[(ct * 16 + li) * 72 + wv * 16 + quad * 4 + r] = f2bf(acc[ct][r]);
        __syncthreads();
        int dr = t >> 2, pc = (t & 3) * 16;
        u32x4* g = (u32x4*)(vt + ((size_t)((b * 4 + head) * 64 + dr)) * 4096 + p0 + pc);
        const u32x4* s2 = (const u32x4*)(T + dr * 72 + pc);
        g[0] = s2[0];
        g[1] = s2[1];
    } else {
        u16* outp = (tensor == 0) ? q : k;
        float sc = (tensor == 0) ? QSCALE : 1.0f;
#pragma unroll
        for (int ct = 0; ct < 4; ++ct)
#pragma unroll
            for (int r = 0; r < 4; ++r) {
                int p = p0 + wv * 16 + quad * 4 + r;
                int d = ct * 16 + li;
                outp[((size_t)((b * 4 + head) * 4096 + p)) * 64 + d] = f2bf(acc[ct][r] * sc);
            }
        if (tensor == 0) {
            // ---- fused rel-bias tables ----
            int bh = b * 4 + head;
            u16* T = Sm;             // [64 p][72 d]
            u16* Ls = Sm + 64 * 72;  // [128 r][72 d]
            __syncthreads();         // all GEMM Sm reads done
#pragma unroll
            for (int ct = 0; ct < 4; ++ct)
#pragma unroll
                for (int r = 0; r < 4; ++r)
                    T[(wv * 16 + quad * 4 + r) * 72 + ct * 16 + li] = f2bf(acc[ct][r] * QSCALE);
            {
                int row = t >> 1, half = t & 1;
                const u32x4* g2 = (const u32x4*)(relwb + row * 64 + half * 32);
                u32x4* s2 = (u32x4*)(Ls + row * 72 + half * 32);
#pragma unroll
                for (int kk = 0; kk < 4; ++kk) s2[kk] = g2[kk];
            }
            __syncthreads();
            u32x4 aq2[2];
            aq2[0] = *(const u32x4*)(T + (wv * 16 + li) * 72 + quad * 8);
            aq2[1] = *(const u32x4*)(T + (wv * 16 + li) * 72 + 32 + quad * 8);

            f32x4 acc2[8];
#pragma unroll
            for (int ct = 0; ct < 8; ++ct) acc2[ct] = (f32x4){0.f, 0.f, 0.f, 0.f};
#pragma unroll
            for (int kc = 0; kc < 2; ++kc) {
                bf16x8 a = bc8(aq2[kc]);
#pragma unroll
                for (int ct = 0; ct < 8; ++ct) {
                    bf16x8 bb = bc8(*(const u32x4*)(Ls + (ct * 16 + li) * 72 + kc * 32 + quad * 8));
                    acc2[ct] = MFMA16(a, bb, acc2[ct]);
                }
            }
#pragma unroll
            for (int ct = 0; ct < 8; ++ct)
#pragma unroll
                for (int r = 0; r < 4; ++r) {
                    int row = wv * 16 + quad * 4 + r;
                    int j = (ct * 16 + li) - 63 + row;  // shift = y = row
                    if (j >= 0 && j < 64)
                        Wabs[((size_t)(bh * 4096 + p0 + row)) * 64 + j] = f2bf(acc2[ct][r]);
                }
            __syncthreads();  // Ls reads done
            {
                int row = t >> 1, half = t & 1;
                const u32x4* g2 = (const u32x4*)(relhb + row * 64 + half * 32);
                u32x4* s2 = (u32x4*)(Ls + row * 72 + half * 32);
#pragma unroll
                for (int kk = 0; kk < 4; ++kk) s2[kk] = g2[kk];
            }
            __syncthreads();
#pragma unroll
            for (int ct = 0; ct < 8; ++ct) acc2[ct] = (f32x4){0.f, 0.f, 0.f, 0.f};
#pragma unroll
            for (int kc = 0; kc < 2; ++kc) {
                bf16x8 a = bc8(aq2[kc]);
#pragma unroll
                for (int ct = 0; ct < 8; ++ct) {
                    bf16x8 bb = bc8(*(const u32x4*)(Ls + (ct * 16 + li) * 72 + kc * 32 + quad * 8));
                    acc2[ct] = MFMA16(a, bb, acc2[ct]);
                }
            }
            // store TRANSPOSED: HabsT[bh][jh][p]
#pragma unroll
            for (int ct = 0; ct < 8; ++ct)
#pragma unroll
                for (int r = 0; r < 4; ++r) {
                    int row = wv * 16 + quad * 4 + r;
                    int j = (ct * 16 + li) - 63 + pm;  // shift = x = pm
                    if (j >= 0 && j < 64)
                        HabsT[((size_t)(bh * 64 + j)) * 4096 + p0 + row] = f2bf(acc2[ct][r]);
                }
        }
    }
}

// ---------------------------------------------------------------------------
// K3: flash attention v8. K-split x4 (1024 blocks, 16 iters), 36.9 KB LDS ->
// 4 blocks/CU (16 waves/CU). R6-style ds_write staging (gll regressed, R8).
// Height bias from transposed HabsT via prefetched coalesced u16 loads (no Hl).
__global__ __launch_bounds__(256, 4) void k_flash(const u16* __restrict__ q,
                                                  const u16* __restrict__ kg,
                                                  const u16* __restrict__ vt,
                                                  const u16* __restrict__ Wabs,
                                                  const u16* __restrict__ HabsT,
                                                  u16* __restrict__ OP,
                                                  float* __restrict__ LS) {
    int pm = blockIdx.x, bh = blockIdx.y, ks = blockIdx.z;
    int p0 = pm * 128;
    __shared__ __align__(16) u16 Kt[2][64 * 72];
    __shared__ __align__(16) u16 Vl[2][64 * 72];
    int t = threadIdx.x, wv = t >> 6, l = t & 63, quad = l >> 4, li = l & 15;
    int rbase = wv * 32;

    // Q B-frags for both row-sets
    u32x4 aq[2][2];
#pragma unroll
    for (int rs = 0; rs < 2; ++rs) {
        const u32x4* qrow =
            (const u32x4*)(q + ((size_t)(bh * 4096 + p0 + rbase + rs * 16 + li)) * 64);
        aq[rs][0] = qrow[quad];
        aq[rs][1] = qrow[4 + quad];
    }

    // width-bias as f32x4 per (rs,ct), aligned to the S^T C-frag
    f32x4 wb4[2][4];
#pragma unroll
    for (int rs = 0; rs < 2; ++rs)
#pragma unroll
        for (int ct = 0; ct < 4; ++ct) {
            const u32* wp = (const u32*)(Wabs +
                                         ((size_t)(bh * 4096 + p0 + rbase + rs * 16 + li)) * 64 +
                                         ct * 16 + quad * 4);
            u32 lo = wp[0], hi = wp[1];
            wb4[rs][ct] = (f32x4){bflo(lo), bfhi(lo), bflo(hi), bfhi(hi)};
        }

    // height-bias source: HabsT[bh][jh][p]; per iter need rows rbase+li, rbase+16+li
    const u16* hbase = HabsT + ((size_t)(bh * 64 + ks * 16)) * 4096 + p0 + rbase;

    int srow = t >> 2, scc = (t & 3) * 16;
    // preload tile 0 into buffer 0
    {
        int j0 = ks * 1024;
        const u32x4* gk = (const u32x4*)(kg + ((size_t)(bh * 4096 + j0 + srow)) * 64 + scc);
        u32x4* sk = (u32x4*)(Kt[0] + srow * 72 + scc);
        sk[0] = gk[0];
        sk[1] = gk[1];
        const u32x4* gv = (const u32x4*)(vt + ((size_t)(bh * 64 + srow)) * 4096 + j0 + scc);
        u32x4* sv = (u32x4*)(Vl[0] + srow * 72 + scc);
        sv[0] = gv[0];
        sv[1] = gv[1];
    }
    u16 hc0 = hbase[li];
    u16 hc1 = hbase[16 + li];

    f32x4 oacc[2][5];
#pragma unroll
    for (int rs = 0; rs < 2; ++rs)
#pragma unroll
        for (int ct = 0; ct < 5; ++ct) oacc[rs][ct] = (f32x4){0.f, 0.f, 0.f, 0.f};

    const s16x4 ones = {(short)0x3F80, (short)0x3F80, (short)0x3F80, (short)0x3F80};

    u32x4 kreg[2], vreg[2];
    u16 hn0, hn1;
    for (int kt = 0; kt < 16; ++kt) {
        __syncthreads();  // tile kt ready in buf[kt&1]; prior reads of buf[kt^1] done
        int cur = kt & 1;
        const u16* Kc = Kt[cur];
        const u16* Vc = Vl[cur];
        if (kt < 15) {
            int j0 = (ks * 16 + kt + 1) * 64;
            const u32x4* gk = (const u32x4*)(kg + ((size_t)(bh * 4096 + j0 + srow)) * 64 + scc);
            kreg[0] = gk[0];
            kreg[1] = gk[1];
            const u32x4* gv = (const u32x4*)(vt + ((size_t)(bh * 64 + srow)) * 4096 + j0 + scc);
            vreg[0] = gv[0];
            vreg[1] = gv[1];
            hn0 = hbase[(size_t)(kt + 1) * 4096 + li];
            hn1 = hbase[(size_t)(kt + 1) * 4096 + 16 + li];
        }

        // S^T = K · Q^T with bias-initialized accumulators
        float hh0 = bf2f(hc0);
        float hh1 = bf2f(hc1);
        f32x4 s[2][4];
#pragma unroll
        for (int ct = 0; ct < 4; ++ct) {
            s[0][ct] = wb4[0][ct] + hh0;
            s[1][ct] = wb4[1][ct] + hh1;
        }
#pragma unroll
        for (int kc = 0; kc < 2; ++kc) {
            bf16x8 b0 = bc8(aq[0][kc]), b1 = bc8(aq[1][kc]);
#pragma unroll
            for (int ct = 0; ct < 4; ++ct) {
                bf16x8 af = bc8(*(const u32x4*)(Kc + (ct * 16 + li) * 72 + kc * 32 + quad * 8));
                s[0][ct] = MFMA16(af, b0, s[0][ct]);
                s[1][ct] = MFMA16(af, b1, s[1][ct]);
            }
        }

        // exp2 + packed bf16 P-fragments (registers only)
        s16x4 pf[2][4];
#pragma unroll
        for (int rs = 0; rs < 2; ++rs)
#pragma unroll
            for (int ct = 0; ct < 4; ++ct) {
                u32x2 pp;
                pp.x = pack2(EXP2F(s[rs][ct][0]), EXP2F(s[rs][ct][1]));
                pp.y = pack2(EXP2F(s[rs][ct][2]), EXP2F(s[rs][ct][3]));
                pf[rs][ct] = __builtin_bit_cast(s16x4, pp);
            }

        // O += P · V ; dt=4 accumulates row sums via ones operand
#pragma unroll
        for (int jt = 0; jt < 4; ++jt) {
            s16x4 a0 = pf[0][jt], a1 = pf[1][jt];
#pragma unroll
            for (int dt = 0; dt < 4; ++dt) {
                s16x4 bv = __builtin_bit_cast(
                    s16x4, *(const u32x2*)(Vc + (dt * 16 + li) * 72 + jt * 16 + quad * 4));
                oacc[0][dt] = MFMA1K(a0, bv, oacc[0][dt]);
                oacc[1][dt] = MFMA1K(a1, bv, oacc[1][dt]);
            }
            oacc[0][4] = MFMA1K(a0, ones, oacc[0][4]);
            oacc[1][4] = MFMA1K(a1, ones, oacc[1][4]);
        }

        // commit prefetched tile to the other buffer
        if (kt < 15) {
            u32x4* sk = (u32x4*)(Kt[cur ^ 1] + srow * 72 + scc);
            sk[0] = kreg[0];
            sk[1] = kreg[1];
            u32x4* sv = (u32x4*)(Vl[cur ^ 1] + srow * 72 + scc);
            sv[0] = vreg[0];
            sv[1] = vreg[1];
            hc0 = hn0;
            hc1 = hn1;
        }
    }

    // store bf16 partials + fp32 row-sums (normalization in k_out2)
#pragma unroll
    for (int rs = 0; rs < 2; ++rs) {
#pragma unroll
        for (int ct = 0; ct < 4; ++ct)
#pragma unroll
            for (int r = 0; r < 4; ++r) {
                int p = p0 + rbase + rs * 16 + quad * 4 + r;
                OP[((size_t)((ks * 8 + bh) * 4096 + p)) * 64 + ct * 16 + li] =
                    f2bf(oacc[rs][ct][r]);
            }
        if (li == 0) {
#pragma unroll
            for (int r = 0; r < 4; ++r) {
                int p = p0 + rbase + rs * 16 + quad * 4 + r;
                LS[(size_t)(ks * 8 + bh) * 4096 + p] = oacc[rs][4][r];
            }
        }
    }
}

// ---------------------------------------------------------------------------
// K4: fused combine (4 K-slices) + out-projection + residual. grid (64 pm, 2 b, 2 coh).
__global__ __launch_bounds__(256) void k_out2(const u16* __restrict__ wob,
                                              const u16* __restrict__ OP,
                                              const float* __restrict__ LS,
                                              const float* __restrict__ x,
                                              float* __restrict__ out) {
    int pm = blockIdx.x, b = blockIdx.y, coh = blockIdx.z;
    int p0 = pm * 64;
    __shared__ __align__(16) u16 Bt[64 * 264];
    int t = threadIdx.x, wv = t >> 6, l = t & 63, quad = l >> 4, li = l & 15;

    {
        int row = t >> 2, head = t & 3;
        int bh = b * 4 + head;
        int p = p0 + row;
        const u32x4* op[4];
        float lsum = 0.f;
#pragma unroll
        for (int s2 = 0; s2 < 4; ++s2) {
            op[s2] = (const u32x4*)(OP + ((size_t)((s2 * 8 + bh) * 4096 + p)) * 64);
            lsum += LS[(size_t)(s2 * 8 + bh) * 4096 + p];
        }
        float linv = 1.0f / lsum;
        u16* dst = Bt + row * 264 + head * 64;
#pragma unroll
        for (int kk = 0; kk < 8; ++kk) {
            u32x4 a = op[0][kk], c = op[1][kk], e = op[2][kk], f = op[3][kk];
            u32x4 pk;
            pk.x = pack2((bflo(a.x) + bflo(c.x) + bflo(e.x) + bflo(f.x)) * linv,
                         (bfhi(a.x) + bfhi(c.x) + bfhi(e.x) + bfhi(f.x)) * linv);
            pk.y = pack2((bflo(a.y) + bflo(c.y) + bflo(e.y) + bflo(f.y)) * linv,
                         (bfhi(a.y) + bfhi(c.y) + bfhi(e.y) + bfhi(f.y)) * linv);
            pk.z = pack2((bflo(a.z) + bflo(c.z) + bflo(e.z) + bflo(f.z)) * linv,
                         (bfhi(a.z) + bfhi(c.z) + bfhi(e.z) + bfhi(f.z)) * linv);
            pk.w = pack2((bflo(a.w) + bflo(c.w) + bflo(e.w) + bflo(f.w)) * linv,
                         (bfhi(a.w) + bfhi(c.w) + bfhi(e.w) + bfhi(f.w)) * linv);
            *(u32x4*)(dst + kk * 8) = pk;
        }
    }
    __syncthreads();

#pragma unroll
    for (int ci = 0; ci < 2; ++ci) {
        int com = coh * 2 + ci;
        int co0 = com * 64;
        f32x4 acc[4] = {{0, 0, 0, 0}, {0, 0, 0, 0}, {0, 0, 0, 0}, {0, 0, 0, 0}};
        const u32x4* arow = (const u32x4*)(wob + (size_t)(co0 + wv * 16 + li) * 256);
#pragma unroll
        for (int kc = 0; kc < 8; ++kc) {
            bf16x8 a = bc8(arow[kc * 4 + quad]);
#pragma unroll
            for (int ct = 0; ct < 4; ++ct) {
                bf16x8 bb = bc8(*(const u32x4*)(Bt + (ct * 16 + li) * 264 + kc * 32 + quad * 8));
                acc[ct] = MFMA16(a, bb, acc[ct]);
            }
        }
#pragma unroll
        for (int ct = 0; ct < 4; ++ct)
#pragma unroll
            for (int r = 0; r < 4; ++r) {
                size_t idx =
                    ((size_t)(b * 256 + co0 + wv * 16 + quad * 4 + r)) * 4096 + p0 + ct * 16 + li;
                out[idx] = acc[ct][r] + x[idx];
            }
    }
}

// ---------------------------------------------------------------------------
extern "C" void kernel_launch(void* const* d_in, const int* in_sizes, int n_in, void* d_out,
                              int out_size, void* d_ws, size_t ws_size, hipStream_t stream) {
    const float* x = (const float*)d_in[0];
    const float* wqkv = (const float*)d_in[1];
    const float* wout = (const float*)d_in[2];
    const float* relh = (const float*)d_in[3];
    const float* relw = (const float*)d_in[4];
    float* out = (float*)d_out;
    char* ws = (char*)d_ws;

    u16* xt = (u16*)(ws + 0);               // 4,194,304 (dead after k_qkv)
    u16* wqb = (u16*)(ws + 4194304);        //   393,216
    u16* wob = (u16*)(ws + 4587520);        //   131,072
    u16* relwb = (u16*)(ws + 4718592);      //    16,384
    u16* relhb = (u16*)(ws + 4734976);      //    16,384
    u16* qb = (u16*)(ws + 4751360);         // 4,194,304
    u16* kb = (u16*)(ws + 8945664);         // 4,194,304
    u16* vtb = (u16*)(ws + 13139968);       // 4,194,304
    u16* Wabs = (u16*)(ws + 17334272);      // 4,194,304
    u16* HabsT = (u16*)(ws + 21528576);     // 4,194,304
    u16* OPart = (u16*)(ws + 25722880);     // 16,777,216 (4 x 8 x 4096 x 64 bf16) end 42.5 MB
    float* LSum = (float*)(ws + 0);         //   524,288 (aliases dead xt)

    k_prep<<<768, 256, 0, stream>>>(x, wqkv, wout, relh, relw, xt, wqb, wob, relhb, relwb);
    k_qkv<<<dim3(64, 12, 2), 256, 0, stream>>>(xt, wqb, relwb, relhb, qb, kb, vtb, Wabs, HabsT);
    k_flash<<<dim3(32, 8, 4), 256, 0, stream>>>(qb, kb, vtb, Wabs, HabsT, OPart, LSum);
    k_out2<<<dim3(64, 2, 2), 256, 0, stream>>>(wob, OPart, LSum, x, out);
}

// Round 10
// 149.437 us; speedup vs baseline: 1.1376x; 1.1376x over previous
//
#include <hip/hip_runtime.h>

typedef unsigned short u16;
typedef unsigned int u32;
typedef __bf16 bf16x8 __attribute__((ext_vector_type(8)));
typedef __bf16 bf16x2 __attribute__((ext_vector_type(2)));
typedef float f32x4 __attribute__((ext_vector_type(4)));
typedef float f32x2 __attribute__((ext_vector_type(2)));
typedef u32 u32x4 __attribute__((ext_vector_type(4)));
typedef u32 u32x2 __attribute__((ext_vector_type(2)));
typedef short s16x4 __attribute__((ext_vector_type(4)));

#define DEVI __device__ __forceinline__

#if defined(__has_builtin)
#if __has_builtin(__builtin_amdgcn_exp2f)
#define EXP2F(x) __builtin_amdgcn_exp2f(x)
#endif
#endif
#ifndef EXP2F
#define EXP2F(x) exp2f(x)
#endif

#define MFMA16(a, b, c) __builtin_amdgcn_mfma_f32_16x16x32_bf16(a, b, c, 0, 0, 0)
#define MFMA1K(a, b, c) __builtin_amdgcn_mfma_f32_16x16x16bf16_1k(a, b, c, 0, 0, 0)

typedef __attribute__((address_space(1))) u32 gu32;
typedef __attribute__((address_space(3))) u32 lu32;
DEVI void gll16(const u16* g, u16* l) {
    __builtin_amdgcn_global_load_lds((const gu32*)g, (lu32*)l, 16, 0, 0);
}
#define WAIT_VM0() __builtin_amdgcn_s_waitcnt(0x0f70)  // vmcnt(0) only

DEVI u16 f2bf(float f) {
    u32 u = __builtin_bit_cast(u32, f);
    u = (u + 0x7FFFu + ((u >> 16) & 1u)) >> 16;
    return (u16)u;
}
DEVI float bf2f(u16 h) {
    u32 u = ((u32)h) << 16;
    return __builtin_bit_cast(float, u);
}
DEVI float bfhi(u32 u) { return __builtin_bit_cast(float, u & 0xFFFF0000u); }
DEVI float bflo(u32 u) { return __builtin_bit_cast(float, u << 16); }
DEVI bf16x8 bc8(u32x4 u) { return __builtin_bit_cast(bf16x8, u); }
DEVI u32 pack2(float a, float b) {
    f32x2 v = {a, b};
    bf16x2 h = __builtin_convertvector(v, bf16x2);
    return __builtin_bit_cast(u32, h);
}

// q scale: dh^-0.5 * log2(e)  (bakes natural-exp into exp2)
#define QSCALE 0.18033688011112042f

// ---------------------------------------------------------------------------
// K0: fused prep. Blocks [0,512): transpose+cast x -> xt[b][p][c] bf16.
//     Blocks [512,768): cast weights + rel tables (rel zero-padded to 128 rows).
__global__ __launch_bounds__(256) void k_prep(const float* __restrict__ x,
                                              const float* __restrict__ wq,
                                              const float* __restrict__ wo,
                                              const float* __restrict__ relh,
                                              const float* __restrict__ relw,
                                              u16* __restrict__ xt, u16* __restrict__ wqb,
                                              u16* __restrict__ wob, u16* __restrict__ relhb,
                                              u16* __restrict__ relwb) {
    int bid = blockIdx.x;
    int t = threadIdx.x;
    if (bid < 512) {
        int pm = bid & 63, cm = (bid >> 6) & 3, b = bid >> 8;
        int p0 = pm * 64, c0 = cm * 64;
        __shared__ float tile[64][65];
#pragma unroll
        for (int it = 0; it < 16; ++it) {
            int idx = it * 256 + t;
            int cl = idx >> 6, pl = idx & 63;
            tile[cl][pl] = x[((size_t)(b * 256 + c0 + cl)) * 4096 + p0 + pl];
        }
        __syncthreads();
#pragma unroll
        for (int it = 0; it < 16; ++it) {
            int idx = it * 256 + t;
            int pl = idx >> 6, cl = idx & 63;
            xt[((size_t)(b * 4096 + p0 + pl)) * 256 + c0 + cl] = f2bf(tile[cl][pl]);
        }
    } else {
        int i0 = (bid - 512) * 256 + t;  // 65536 stride
#pragma unroll
        for (int i = i0; i < 196608; i += 65536) wqb[i] = f2bf(wq[i]);
        if (i0 < 65536) wob[i0] = f2bf(wo[i0]);
        if (i0 < 8192) {
            relhb[i0] = (i0 < 8128) ? f2bf(relh[i0]) : (u16)0;
            relwb[i0] = (i0 < 8128) ? f2bf(relw[i0]) : (u16)0;
        }
    }
}

// ---------------------------------------------------------------------------
// K1: QKV projection GEMM + fused rel-bias tables (B-tile staged via gll, mod-32 swizzle).
// Height table stored TRANSPOSED: HabsT[bh][jh][p].
__global__ __launch_bounds__(256) void k_qkv(const u16* __restrict__ xt, const u16* __restrict__ wqb,
                                             const u16* __restrict__ relwb,
                                             const u16* __restrict__ relhb,
                                             u16* __restrict__ q, u16* __restrict__ k,
                                             u16* __restrict__ vt, u16* __restrict__ Wabs,
                                             u16* __restrict__ HabsT) {
    int pm = blockIdx.x, on = blockIdx.y, b = blockIdx.z;
    int p0 = pm * 64, o0 = on * 64;
    __shared__ __align__(16) u16 Sm[64 * 256];  // 32 KB B-tile; later T[64*72]+Ls[128*72]
    int t = threadIdx.x;
    int wv = t >> 6, l = t & 63, quad = l >> 4, li = l & 15;

    u32x4 areg[8];
    const u32x4* arow = (const u32x4*)(xt + ((size_t)(b * 4096 + p0 + wv * 16 + li)) * 256);
#pragma unroll
    for (int kc = 0; kc < 8; ++kc) areg[kc] = arow[kc * 4 + quad];

    {
        int pc = l & 31;
#pragma unroll
        for (int i = 0; i < 8; ++i) {
            int r = wv * 16 + i * 2 + (l >> 5);
            gll16(wqb + (size_t)(o0 + r) * 256 + ((pc + r) & 31) * 8,
                  Sm + (wv * 16 + i * 2) * 256);
        }
    }
    WAIT_VM0();
    __syncthreads();

    f32x4 acc[4] = {{0, 0, 0, 0}, {0, 0, 0, 0}, {0, 0, 0, 0}, {0, 0, 0, 0}};
#pragma unroll
    for (int kc = 0; kc < 8; ++kc) {
        bf16x8 a = bc8(areg[kc]);
#pragma unroll
        for (int ct = 0; ct < 4; ++ct) {
            bf16x8 bb = bc8(*(const u32x4*)(Sm + (ct * 16 + li) * 256 +
                                            (((kc * 4 + quad) - (ct * 16 + li)) & 31) * 8));
            acc[ct] = MFMA16(a, bb, acc[ct]);
        }
    }

    int tensor = on >> 2, head = on & 3;
    if (tensor == 2) {
        __syncthreads();
        u16* T = Sm;  // [64 d][72 p]
#pragma unroll
        for (int ct = 0; ct < 4; ++ct)
#pragma unroll
            for (int r = 0; r < 4; ++r)
                T[(ct * 16 + li) * 72 + wv * 16 + quad * 4 + r] = f2bf(acc[ct][r]);
        __syncthreads();
        int dr = t >> 2, pc = (t & 3) * 16;
        u32x4* g = (u32x4*)(vt + ((size_t)((b * 4 + head) * 64 + dr)) * 4096 + p0 + pc);
        const u32x4* s2 = (const u32x4*)(T + dr * 72 + pc);
        g[0] = s2[0];
        g[1] = s2[1];
    } else {
        u16* outp = (tensor == 0) ? q : k;
        float sc = (tensor == 0) ? QSCALE : 1.0f;
#pragma unroll
        for (int ct = 0; ct < 4; ++ct)
#pragma unroll
            for (int r = 0; r < 4; ++r) {
                int p = p0 + wv * 16 + quad * 4 + r;
                int d = ct * 16 + li;
                outp[((size_t)((b * 4 + head) * 4096 + p)) * 64 + d] = f2bf(acc[ct][r] * sc);
            }
        if (tensor == 0) {
            // ---- fused rel-bias tables ----
            int bh = b * 4 + head;
            u16* T = Sm;             // [64 p][72 d]
            u16* Ls = Sm + 64 * 72;  // [128 r][72 d]
            __syncthreads();         // all GEMM Sm reads done
#pragma unroll
            for (int ct = 0; ct < 4; ++ct)
#pragma unroll
                for (int r = 0; r < 4; ++r)
                    T[(wv * 16 + quad * 4 + r) * 72 + ct * 16 + li] = f2bf(acc[ct][r] * QSCALE);
            {
                int row = t >> 1, half = t & 1;
                const u32x4* g2 = (const u32x4*)(relwb + row * 64 + half * 32);
                u32x4* s2 = (u32x4*)(Ls + row * 72 + half * 32);
#pragma unroll
                for (int kk = 0; kk < 4; ++kk) s2[kk] = g2[kk];
            }
            __syncthreads();
            u32x4 aq2[2];
            aq2[0] = *(const u32x4*)(T + (wv * 16 + li) * 72 + quad * 8);
            aq2[1] = *(const u32x4*)(T + (wv * 16 + li) * 72 + 32 + quad * 8);

            f32x4 acc2[8];
#pragma unroll
            for (int ct = 0; ct < 8; ++ct) acc2[ct] = (f32x4){0.f, 0.f, 0.f, 0.f};
#pragma unroll
            for (int kc = 0; kc < 2; ++kc) {
                bf16x8 a = bc8(aq2[kc]);
#pragma unroll
                for (int ct = 0; ct < 8; ++ct) {
                    bf16x8 bb = bc8(*(const u32x4*)(Ls + (ct * 16 + li) * 72 + kc * 32 + quad * 8));
                    acc2[ct] = MFMA16(a, bb, acc2[ct]);
                }
            }
#pragma unroll
            for (int ct = 0; ct < 8; ++ct)
#pragma unroll
                for (int r = 0; r < 4; ++r) {
                    int row = wv * 16 + quad * 4 + r;
                    int j = (ct * 16 + li) - 63 + row;  // shift = y = row
                    if (j >= 0 && j < 64)
                        Wabs[((size_t)(bh * 4096 + p0 + row)) * 64 + j] = f2bf(acc2[ct][r]);
                }
            __syncthreads();  // Ls reads done
            {
                int row = t >> 1, half = t & 1;
                const u32x4* g2 = (const u32x4*)(relhb + row * 64 + half * 32);
                u32x4* s2 = (u32x4*)(Ls + row * 72 + half * 32);
#pragma unroll
                for (int kk = 0; kk < 4; ++kk) s2[kk] = g2[kk];
            }
            __syncthreads();
#pragma unroll
            for (int ct = 0; ct < 8; ++ct) acc2[ct] = (f32x4){0.f, 0.f, 0.f, 0.f};
#pragma unroll
            for (int kc = 0; kc < 2; ++kc) {
                bf16x8 a = bc8(aq2[kc]);
#pragma unroll
                for (int ct = 0; ct < 8; ++ct) {
                    bf16x8 bb = bc8(*(const u32x4*)(Ls + (ct * 16 + li) * 72 + kc * 32 + quad * 8));
                    acc2[ct] = MFMA16(a, bb, acc2[ct]);
                }
            }
            // store TRANSPOSED: HabsT[bh][jh][p]
#pragma unroll
            for (int ct = 0; ct < 8; ++ct)
#pragma unroll
                for (int r = 0; r < 4; ++r) {
                    int row = wv * 16 + quad * 4 + r;
                    int j = (ct * 16 + li) - 63 + pm;  // shift = x = pm
                    if (j >= 0 && j < 64)
                        HabsT[((size_t)(bh * 64 + j)) * 4096 + p0 + row] = f2bf(acc2[ct][r]);
                }
        }
    }
}

// ---------------------------------------------------------------------------
// K3: flash attention v9. Same as v8 (K-split x4, 1024 blocks, 16 iters,
// 36.9 KB LDS) but launch_bounds (256,2): R9's (256,4) forced VGPR 80->64 and
// SPILLED (WRITE_SIZE 8.4->36 MB = scratch traffic). Natural VGPR ~80-104
// allows 4 waves/SIMD anyway; occupancy is then LDS/grid-limited at 4 blk/CU.
__global__ __launch_bounds__(256, 2) void k_flash(const u16* __restrict__ q,
                                                  const u16* __restrict__ kg,
                                                  const u16* __restrict__ vt,
                                                  const u16* __restrict__ Wabs,
                                                  const u16* __restrict__ HabsT,
                                                  u16* __restrict__ OP,
                                                  float* __restrict__ LS) {
    int pm = blockIdx.x, bh = blockIdx.y, ks = blockIdx.z;
    int p0 = pm * 128;
    __shared__ __align__(16) u16 Kt[2][64 * 72];
    __shared__ __align__(16) u16 Vl[2][64 * 72];
    int t = threadIdx.x, wv = t >> 6, l = t & 63, quad = l >> 4, li = l & 15;
    int rbase = wv * 32;

    // Q B-frags for both row-sets
    u32x4 aq[2][2];
#pragma unroll
    for (int rs = 0; rs < 2; ++rs) {
        const u32x4* qrow =
            (const u32x4*)(q + ((size_t)(bh * 4096 + p0 + rbase + rs * 16 + li)) * 64);
        aq[rs][0] = qrow[quad];
        aq[rs][1] = qrow[4 + quad];
    }

    // width-bias as f32x4 per (rs,ct), aligned to the S^T C-frag
    f32x4 wb4[2][4];
#pragma unroll
    for (int rs = 0; rs < 2; ++rs)
#pragma unroll
        for (int ct = 0; ct < 4; ++ct) {
            const u32* wp = (const u32*)(Wabs +
                                         ((size_t)(bh * 4096 + p0 + rbase + rs * 16 + li)) * 64 +
                                         ct * 16 + quad * 4);
            u32 lo = wp[0], hi = wp[1];
            wb4[rs][ct] = (f32x4){bflo(lo), bfhi(lo), bflo(hi), bfhi(hi)};
        }

    // height-bias source: HabsT[bh][jh][p]; per iter need rows rbase+li, rbase+16+li
    const u16* hbase = HabsT + ((size_t)(bh * 64 + ks * 16)) * 4096 + p0 + rbase;

    int srow = t >> 2, scc = (t & 3) * 16;
    // preload tile 0 into buffer 0
    {
        int j0 = ks * 1024;
        const u32x4* gk = (const u32x4*)(kg + ((size_t)(bh * 4096 + j0 + srow)) * 64 + scc);
        u32x4* sk = (u32x4*)(Kt[0] + srow * 72 + scc);
        sk[0] = gk[0];
        sk[1] = gk[1];
        const u32x4* gv = (const u32x4*)(vt + ((size_t)(bh * 64 + srow)) * 4096 + j0 + scc);
        u32x4* sv = (u32x4*)(Vl[0] + srow * 72 + scc);
        sv[0] = gv[0];
        sv[1] = gv[1];
    }
    u16 hc0 = hbase[li];
    u16 hc1 = hbase[16 + li];

    f32x4 oacc[2][5];
#pragma unroll
    for (int rs = 0; rs < 2; ++rs)
#pragma unroll
        for (int ct = 0; ct < 5; ++ct) oacc[rs][ct] = (f32x4){0.f, 0.f, 0.f, 0.f};

    const s16x4 ones = {(short)0x3F80, (short)0x3F80, (short)0x3F80, (short)0x3F80};

    u32x4 kreg[2], vreg[2];
    u16 hn0, hn1;
    for (int kt = 0; kt < 16; ++kt) {
        __syncthreads();  // tile kt ready in buf[kt&1]; prior reads of buf[kt^1] done
        int cur = kt & 1;
        const u16* Kc = Kt[cur];
        const u16* Vc = Vl[cur];
        if (kt < 15) {
            int j0 = (ks * 16 + kt + 1) * 64;
            const u32x4* gk = (const u32x4*)(kg + ((size_t)(bh * 4096 + j0 + srow)) * 64 + scc);
            kreg[0] = gk[0];
            kreg[1] = gk[1];
            const u32x4* gv = (const u32x4*)(vt + ((size_t)(bh * 64 + srow)) * 4096 + j0 + scc);
            vreg[0] = gv[0];
            vreg[1] = gv[1];
            hn0 = hbase[(size_t)(kt + 1) * 4096 + li];
            hn1 = hbase[(size_t)(kt + 1) * 4096 + 16 + li];
        }

        // S^T = K · Q^T with bias-initialized accumulators
        float hh0 = bf2f(hc0);
        float hh1 = bf2f(hc1);
        f32x4 s[2][4];
#pragma unroll
        for (int ct = 0; ct < 4; ++ct) {
            s[0][ct] = wb4[0][ct] + hh0;
            s[1][ct] = wb4[1][ct] + hh1;
        }
#pragma unroll
        for (int kc = 0; kc < 2; ++kc) {
            bf16x8 b0 = bc8(aq[0][kc]), b1 = bc8(aq[1][kc]);
#pragma unroll
            for (int ct = 0; ct < 4; ++ct) {
                bf16x8 af = bc8(*(const u32x4*)(Kc + (ct * 16 + li) * 72 + kc * 32 + quad * 8));
                s[0][ct] = MFMA16(af, b0, s[0][ct]);
                s[1][ct] = MFMA16(af, b1, s[1][ct]);
            }
        }

        // exp2 + packed bf16 P-fragments (registers only)
        s16x4 pf[2][4];
#pragma unroll
        for (int rs = 0; rs < 2; ++rs)
#pragma unroll
            for (int ct = 0; ct < 4; ++ct) {
                u32x2 pp;
                pp.x = pack2(EXP2F(s[rs][ct][0]), EXP2F(s[rs][ct][1]));
                pp.y = pack2(EXP2F(s[rs][ct][2]), EXP2F(s[rs][ct][3]));
                pf[rs][ct] = __builtin_bit_cast(s16x4, pp);
            }

        // O += P · V ; dt=4 accumulates row sums via ones operand
#pragma unroll
        for (int jt = 0; jt < 4; ++jt) {
            s16x4 a0 = pf[0][jt], a1 = pf[1][jt];
#pragma unroll
            for (int dt = 0; dt < 4; ++dt) {
                s16x4 bv = __builtin_bit_cast(
                    s16x4, *(const u32x2*)(Vc + (dt * 16 + li) * 72 + jt * 16 + quad * 4));
                oacc[0][dt] = MFMA1K(a0, bv, oacc[0][dt]);
                oacc[1][dt] = MFMA1K(a1, bv, oacc[1][dt]);
            }
            oacc[0][4] = MFMA1K(a0, ones, oacc[0][4]);
            oacc[1][4] = MFMA1K(a1, ones, oacc[1][4]);
        }

        // commit prefetched tile to the other buffer
        if (kt < 15) {
            u32x4* sk = (u32x4*)(Kt[cur ^ 1] + srow * 72 + scc);
            sk[0] = kreg[0];
            sk[1] = kreg[1];
            u32x4* sv = (u32x4*)(Vl[cur ^ 1] + srow * 72 + scc);
            sv[0] = vreg[0];
            sv[1] = vreg[1];
            hc0 = hn0;
            hc1 = hn1;
        }
    }

    // store bf16 partials + fp32 row-sums (normalization in k_out2)
#pragma unroll
    for (int rs = 0; rs < 2; ++rs) {
#pragma unroll
        for (int ct = 0; ct < 4; ++ct)
#pragma unroll
            for (int r = 0; r < 4; ++r) {
                int p = p0 + rbase + rs * 16 + quad * 4 + r;
                OP[((size_t)((ks * 8 + bh) * 4096 + p)) * 64 + ct * 16 + li] =
                    f2bf(oacc[rs][ct][r]);
            }
        if (li == 0) {
#pragma unroll
            for (int r = 0; r < 4; ++r) {
                int p = p0 + rbase + rs * 16 + quad * 4 + r;
                LS[(size_t)(ks * 8 + bh) * 4096 + p] = oacc[rs][4][r];
            }
        }
    }
}

// ---------------------------------------------------------------------------
// K4: fused combine (4 K-slices) + out-projection + residual. grid (64 pm, 2 b, 2 coh).
__global__ __launch_bounds__(256) void k_out2(const u16* __restrict__ wob,
                                              const u16* __restrict__ OP,
                                              const float* __restrict__ LS,
                                              const float* __restrict__ x,
                                              float* __restrict__ out) {
    int pm = blockIdx.x, b = blockIdx.y, coh = blockIdx.z;
    int p0 = pm * 64;
    __shared__ __align__(16) u16 Bt[64 * 264];
    int t = threadIdx.x, wv = t >> 6, l = t & 63, quad = l >> 4, li = l & 15;

    {
        int row = t >> 2, head = t & 3;
        int bh = b * 4 + head;
        int p = p0 + row;
        const u32x4* op[4];
        float lsum = 0.f;
#pragma unroll
        for (int s2 = 0; s2 < 4; ++s2) {
            op[s2] = (const u32x4*)(OP + ((size_t)((s2 * 8 + bh) * 4096 + p)) * 64);
            lsum += LS[(size_t)(s2 * 8 + bh) * 4096 + p];
        }
        float linv = 1.0f / lsum;
        u16* dst = Bt + row * 264 + head * 64;
#pragma unroll
        for (int kk = 0; kk < 8; ++kk) {
            u32x4 a = op[0][kk], c = op[1][kk], e = op[2][kk], f = op[3][kk];
            u32x4 pk;
            pk.x = pack2((bflo(a.x) + bflo(c.x) + bflo(e.x) + bflo(f.x)) * linv,
                         (bfhi(a.x) + bfhi(c.x) + bfhi(e.x) + bfhi(f.x)) * linv);
            pk.y = pack2((bflo(a.y) + bflo(c.y) + bflo(e.y) + bflo(f.y)) * linv,
                         (bfhi(a.y) + bfhi(c.y) + bfhi(e.y) + bfhi(f.y)) * linv);
            pk.z = pack2((bflo(a.z) + bflo(c.z) + bflo(e.z) + bflo(f.z)) * linv,
                         (bfhi(a.z) + bfhi(c.z) + bfhi(e.z) + bfhi(f.z)) * linv);
            pk.w = pack2((bflo(a.w) + bflo(c.w) + bflo(e.w) + bflo(f.w)) * linv,
                         (bfhi(a.w) + bfhi(c.w) + bfhi(e.w) + bfhi(f.w)) * linv);
            *(u32x4*)(dst + kk * 8) = pk;
        }
    }
    __syncthreads();

#pragma unroll
    for (int ci = 0; ci < 2; ++ci) {
        int com = coh * 2 + ci;
        int co0 = com * 64;
        f32x4 acc[4] = {{0, 0, 0, 0}, {0, 0, 0, 0}, {0, 0, 0, 0}, {0, 0, 0, 0}};
        const u32x4* arow = (const u32x4*)(wob + (size_t)(co0 + wv * 16 + li) * 256);
#pragma unroll
        for (int kc = 0; kc < 8; ++kc) {
            bf16x8 a = bc8(arow[kc * 4 + quad]);
#pragma unroll
            for (int ct = 0; ct < 4; ++ct) {
                bf16x8 bb = bc8(*(const u32x4*)(Bt + (ct * 16 + li) * 264 + kc * 32 + quad * 8));
                acc[ct] = MFMA16(a, bb, acc[ct]);
            }
        }
#pragma unroll
        for (int ct = 0; ct < 4; ++ct)
#pragma unroll
            for (int r = 0; r < 4; ++r) {
                size_t idx =
                    ((size_t)(b * 256 + co0 + wv * 16 + quad * 4 + r)) * 4096 + p0 + ct * 16 + li;
                out[idx] = acc[ct][r] + x[idx];
            }
    }
}

// ---------------------------------------------------------------------------
extern "C" void kernel_launch(void* const* d_in, const int* in_sizes, int n_in, void* d_out,
                              int out_size, void* d_ws, size_t ws_size, hipStream_t stream) {
    const float* x = (const float*)d_in[0];
    const float* wqkv = (const float*)d_in[1];
    const float* wout = (const float*)d_in[2];
    const float* relh = (const float*)d_in[3];
    const float* relw = (const float*)d_in[4];
    float* out = (float*)d_out;
    char* ws = (char*)d_ws;

    u16* xt = (u16*)(ws + 0);               // 4,194,304 (dead after k_qkv)
    u16* wqb = (u16*)(ws + 4194304);        //   393,216
    u16* wob = (u16*)(ws + 4587520);        //   131,072
    u16* relwb = (u16*)(ws + 4718592);      //    16,384
    u16* relhb = (u16*)(ws + 4734976);      //    16,384
    u16* qb = (u16*)(ws + 4751360);         // 4,194,304
    u16* kb = (u16*)(ws + 8945664);         // 4,194,304
    u16* vtb = (u16*)(ws + 13139968);       // 4,194,304
    u16* Wabs = (u16*)(ws + 17334272);      // 4,194,304
    u16* HabsT = (u16*)(ws + 21528576);     // 4,194,304
    u16* OPart = (u16*)(ws + 25722880);     // 16,777,216 (4 x 8 x 4096 x 64 bf16) end 42.5 MB
    float* LSum = (float*)(ws + 0);         //   524,288 (aliases dead xt)

    k_prep<<<768, 256, 0, stream>>>(x, wqkv, wout, relh, relw, xt, wqb, wob, relhb, relwb);
    k_qkv<<<dim3(64, 12, 2), 256, 0, stream>>>(xt, wqb, relwb, relhb, qb, kb, vtb, Wabs, HabsT);
    k_flash<<<dim3(32, 8, 4), 256, 0, stream>>>(qb, kb, vtb, Wabs, HabsT, OPart, LSum);
    k_out2<<<dim3(64, 2, 2), 256, 0, stream>>>(wob, OPart, LSum, x, out);
}

// Round 11
// 148.805 us; speedup vs baseline: 1.1424x; 1.0042x over previous
//
#include <hip/hip_runtime.h>

typedef unsigned short u16;
typedef unsigned int u32;
typedef __bf16 bf16x8 __attribute__((ext_vector_type(8)));
typedef __bf16 bf16x2 __attribute__((ext_vector_type(2)));
typedef float f32x4 __attribute__((ext_vector_type(4)));
typedef float f32x2 __attribute__((ext_vector_type(2)));
typedef u32 u32x4 __attribute__((ext_vector_type(4)));
typedef u32 u32x2 __attribute__((ext_vector_type(2)));
typedef short s16x4 __attribute__((ext_vector_type(4)));

#define DEVI __device__ __forceinline__

#if defined(__has_builtin)
#if __has_builtin(__builtin_amdgcn_exp2f)
#define EXP2F(x) __builtin_amdgcn_exp2f(x)
#endif
#endif
#ifndef EXP2F
#define EXP2F(x) exp2f(x)
#endif

#define MFMA16(a, b, c) __builtin_amdgcn_mfma_f32_16x16x32_bf16(a, b, c, 0, 0, 0)
#define MFMA1K(a, b, c) __builtin_amdgcn_mfma_f32_16x16x16bf16_1k(a, b, c, 0, 0, 0)

typedef __attribute__((address_space(1))) u32 gu32;
typedef __attribute__((address_space(3))) u32 lu32;
DEVI void gll16(const u16* g, u16* l) {
    __builtin_amdgcn_global_load_lds((const gu32*)g, (lu32*)l, 16, 0, 0);
}
#define WAIT_VM0() __builtin_amdgcn_s_waitcnt(0x0f70)  // vmcnt(0) only

DEVI u16 f2bf(float f) {
    u32 u = __builtin_bit_cast(u32, f);
    u = (u + 0x7FFFu + ((u >> 16) & 1u)) >> 16;
    return (u16)u;
}
DEVI float bf2f(u16 h) {
    u32 u = ((u32)h) << 16;
    return __builtin_bit_cast(float, u);
}
DEVI float bfhi(u32 u) { return __builtin_bit_cast(float, u & 0xFFFF0000u); }
DEVI float bflo(u32 u) { return __builtin_bit_cast(float, u << 16); }
DEVI bf16x8 bc8(u32x4 u) { return __builtin_bit_cast(bf16x8, u); }
DEVI u32 pack2(float a, float b) {
    f32x2 v = {a, b};
    bf16x2 h = __builtin_convertvector(v, bf16x2);
    return __builtin_bit_cast(u32, h);
}

// q scale: dh^-0.5 * log2(e)  (bakes natural-exp into exp2)
#define QSCALE 0.18033688011112042f

// ---------------------------------------------------------------------------
// K0: fused prep. Blocks [0,512): transpose+cast x -> xt[b][p][c] bf16.
//     Blocks [512,768): cast weights + rel tables (rel zero-padded to 128 rows).
__global__ __launch_bounds__(256) void k_prep(const float* __restrict__ x,
                                              const float* __restrict__ wq,
                                              const float* __restrict__ wo,
                                              const float* __restrict__ relh,
                                              const float* __restrict__ relw,
                                              u16* __restrict__ xt, u16* __restrict__ wqb,
                                              u16* __restrict__ wob, u16* __restrict__ relhb,
                                              u16* __restrict__ relwb) {
    int bid = blockIdx.x;
    int t = threadIdx.x;
    if (bid < 512) {
        int pm = bid & 63, cm = (bid >> 6) & 3, b = bid >> 8;
        int p0 = pm * 64, c0 = cm * 64;
        __shared__ float tile[64][65];
#pragma unroll
        for (int it = 0; it < 16; ++it) {
            int idx = it * 256 + t;
            int cl = idx >> 6, pl = idx & 63;
            tile[cl][pl] = x[((size_t)(b * 256 + c0 + cl)) * 4096 + p0 + pl];
        }
        __syncthreads();
#pragma unroll
        for (int it = 0; it < 16; ++it) {
            int idx = it * 256 + t;
            int pl = idx >> 6, cl = idx & 63;
            xt[((size_t)(b * 4096 + p0 + pl)) * 256 + c0 + cl] = f2bf(tile[cl][pl]);
        }
    } else {
        int i0 = (bid - 512) * 256 + t;  // 65536 stride
#pragma unroll
        for (int i = i0; i < 196608; i += 65536) wqb[i] = f2bf(wq[i]);
        if (i0 < 65536) wob[i0] = f2bf(wo[i0]);
        if (i0 < 8192) {
            relhb[i0] = (i0 < 8128) ? f2bf(relh[i0]) : (u16)0;
            relwb[i0] = (i0 < 8128) ? f2bf(relw[i0]) : (u16)0;
        }
    }
}

// ---------------------------------------------------------------------------
// K1: QKV projection GEMM + fused rel-bias tables (B-tile staged via gll, mod-32 swizzle).
// Height table stored TRANSPOSED: HabsT[bh][jh][p].
__global__ __launch_bounds__(256) void k_qkv(const u16* __restrict__ xt, const u16* __restrict__ wqb,
                                             const u16* __restrict__ relwb,
                                             const u16* __restrict__ relhb,
                                             u16* __restrict__ q, u16* __restrict__ k,
                                             u16* __restrict__ vt, u16* __restrict__ Wabs,
                                             u16* __restrict__ HabsT) {
    int pm = blockIdx.x, on = blockIdx.y, b = blockIdx.z;
    int p0 = pm * 64, o0 = on * 64;
    __shared__ __align__(16) u16 Sm[64 * 256];  // 32 KB B-tile; later T[64*72]+Ls[128*72]
    int t = threadIdx.x;
    int wv = t >> 6, l = t & 63, quad = l >> 4, li = l & 15;

    u32x4 areg[8];
    const u32x4* arow = (const u32x4*)(xt + ((size_t)(b * 4096 + p0 + wv * 16 + li)) * 256);
#pragma unroll
    for (int kc = 0; kc < 8; ++kc) areg[kc] = arow[kc * 4 + quad];

    {
        int pc = l & 31;
#pragma unroll
        for (int i = 0; i < 8; ++i) {
            int r = wv * 16 + i * 2 + (l >> 5);
            gll16(wqb + (size_t)(o0 + r) * 256 + ((pc + r) & 31) * 8,
                  Sm + (wv * 16 + i * 2) * 256);
        }
    }
    WAIT_VM0();
    __syncthreads();

    f32x4 acc[4] = {{0, 0, 0, 0}, {0, 0, 0, 0}, {0, 0, 0, 0}, {0, 0, 0, 0}};
#pragma unroll
    for (int kc = 0; kc < 8; ++kc) {
        bf16x8 a = bc8(areg[kc]);
#pragma unroll
        for (int ct = 0; ct < 4; ++ct) {
            bf16x8 bb = bc8(*(const u32x4*)(Sm + (ct * 16 + li) * 256 +
                                            (((kc * 4 + quad) - (ct * 16 + li)) & 31) * 8));
            acc[ct] = MFMA16(a, bb, acc[ct]);
        }
    }

    int tensor = on >> 2, head = on & 3;
    if (tensor == 2) {
        __syncthreads();
        u16* T = Sm;  // [64 d][72 p]
#pragma unroll
        for (int ct = 0; ct < 4; ++ct)
#pragma unroll
            for (int r = 0; r < 4; ++r)
                T[(ct * 16 + li) * 72 + wv * 16 + quad * 4 + r] = f2bf(acc[ct][r]);
        __syncthreads();
        int dr = t >> 2, pc = (t & 3) * 16;
        u32x4* g = (u32x4*)(vt + ((size_t)((b * 4 + head) * 64 + dr)) * 4096 + p0 + pc);
        const u32x4* s2 = (const u32x4*)(T + dr * 72 + pc);
        g[0] = s2[0];
        g[1] = s2[1];
    } else {
        u16* outp = (tensor == 0) ? q : k;
        float sc = (tensor == 0) ? QSCALE : 1.0f;
#pragma unroll
        for (int ct = 0; ct < 4; ++ct)
#pragma unroll
            for (int r = 0; r < 4; ++r) {
                int p = p0 + wv * 16 + quad * 4 + r;
                int d = ct * 16 + li;
                outp[((size_t)((b * 4 + head) * 4096 + p)) * 64 + d] = f2bf(acc[ct][r] * sc);
            }
        if (tensor == 0) {
            // ---- fused rel-bias tables ----
            int bh = b * 4 + head;
            u16* T = Sm;             // [64 p][72 d]
            u16* Ls = Sm + 64 * 72;  // [128 r][72 d]
            __syncthreads();  // all GEMM Sm reads done
#pragma unroll
            for (int ct = 0; ct < 4; ++ct)
#pragma unroll
                for (int r = 0; r < 4; ++r)
                    T[(wv * 16 + quad * 4 + r) * 72 + ct * 16 + li] = f2bf(acc[ct][r] * QSCALE);
            {
                int row = t >> 1, half = t & 1;
                const u32x4* g2 = (const u32x4*)(relwb + row * 64 + half * 32);
                u32x4* s2 = (u32x4*)(Ls + row * 72 + half * 32);
#pragma unroll
                for (int kk = 0; kk < 4; ++kk) s2[kk] = g2[kk];
            }
            __syncthreads();
            u32x4 aq2[2];
            aq2[0] = *(const u32x4*)(T + (wv * 16 + li) * 72 + quad * 8);
            aq2[1] = *(const u32x4*)(T + (wv * 16 + li) * 72 + 32 + quad * 8);

            f32x4 acc2[8];
#pragma unroll
            for (int ct = 0; ct < 8; ++ct) acc2[ct] = (f32x4){0.f, 0.f, 0.f, 0.f};
#pragma unroll
            for (int kc = 0; kc < 2; ++kc) {
                bf16x8 a = bc8(aq2[kc]);
#pragma unroll
                for (int ct = 0; ct < 8; ++ct) {
                    bf16x8 bb = bc8(*(const u32x4*)(Ls + (ct * 16 + li) * 72 + kc * 32 + quad * 8));
                    acc2[ct] = MFMA16(a, bb, acc2[ct]);
                }
            }
#pragma unroll
            for (int ct = 0; ct < 8; ++ct)
#pragma unroll
                for (int r = 0; r < 4; ++r) {
                    int row = wv * 16 + quad * 4 + r;
                    int j = (ct * 16 + li) - 63 + row;  // shift = y = row
                    if (j >= 0 && j < 64)
                        Wabs[((size_t)(bh * 4096 + p0 + row)) * 64 + j] = f2bf(acc2[ct][r]);
                }
            __syncthreads();  // Ls reads done
            {
                int row = t >> 1, half = t & 1;
                const u32x4* g2 = (const u32x4*)(relhb + row * 64 + half * 32);
                u32x4* s2 = (u32x4*)(Ls + row * 72 + half * 32);
#pragma unroll
                for (int kk = 0; kk < 4; ++kk) s2[kk] = g2[kk];
            }
            __syncthreads();
#pragma unroll
            for (int ct = 0; ct < 8; ++ct) acc2[ct] = (f32x4){0.f, 0.f, 0.f, 0.f};
#pragma unroll
            for (int kc = 0; kc < 2; ++kc) {
                bf16x8 a = bc8(aq2[kc]);
#pragma unroll
                for (int ct = 0; ct < 8; ++ct) {
                    bf16x8 bb = bc8(*(const u32x4*)(Ls + (ct * 16 + li) * 72 + kc * 32 + quad * 8));
                    acc2[ct] = MFMA16(a, bb, acc2[ct]);
                }
            }
            // store TRANSPOSED: HabsT[bh][jh][p]
#pragma unroll
            for (int ct = 0; ct < 8; ++ct)
#pragma unroll
                for (int r = 0; r < 4; ++r) {
                    int row = wv * 16 + quad * 4 + r;
                    int j = (ct * 16 + li) - 63 + pm;  // shift = x = pm
                    if (j >= 0 && j < 64)
                        HabsT[((size_t)(bh * 64 + j)) * 4096 + p0 + row] = f2bf(acc2[ct][r]);
                }
        }
    }
}

// ---------------------------------------------------------------------------
// K3: flash attention v10. K-split x2 (512 blocks, 32 iters), 36.9 KB LDS,
// launch_bounds (256,2) (no VGPR squeeze -> no spills; R9/R10 A/B).
// Height bias from transposed HabsT via prefetched coalesced u16 loads.
__global__ __launch_bounds__(256, 2) void k_flash(const u16* __restrict__ q,
                                                  const u16* __restrict__ kg,
                                                  const u16* __restrict__ vt,
                                                  const u16* __restrict__ Wabs,
                                                  const u16* __restrict__ HabsT,
                                                  u16* __restrict__ OP,
                                                  float* __restrict__ LS) {
    int pm = blockIdx.x, bh = blockIdx.y, ks = blockIdx.z;
    int p0 = pm * 128;
    __shared__ __align__(16) u16 Kt[2][64 * 72];
    __shared__ __align__(16) u16 Vl[2][64 * 72];
    int t = threadIdx.x, wv = t >> 6, l = t & 63, quad = l >> 4, li = l & 15;
    int rbase = wv * 32;

    // Q B-frags for both row-sets
    u32x4 aq[2][2];
#pragma unroll
    for (int rs = 0; rs < 2; ++rs) {
        const u32x4* qrow =
            (const u32x4*)(q + ((size_t)(bh * 4096 + p0 + rbase + rs * 16 + li)) * 64);
        aq[rs][0] = qrow[quad];
        aq[rs][1] = qrow[4 + quad];
    }

    // width-bias as f32x4 per (rs,ct), aligned to the S^T C-frag
    f32x4 wb4[2][4];
#pragma unroll
    for (int rs = 0; rs < 2; ++rs)
#pragma unroll
        for (int ct = 0; ct < 4; ++ct) {
            const u32* wp = (const u32*)(Wabs +
                                         ((size_t)(bh * 4096 + p0 + rbase + rs * 16 + li)) * 64 +
                                         ct * 16 + quad * 4);
            u32 lo = wp[0], hi = wp[1];
            wb4[rs][ct] = (f32x4){bflo(lo), bfhi(lo), bflo(hi), bfhi(hi)};
        }

    // height-bias source: HabsT[bh][jh][p]; per iter rows rbase+li, rbase+16+li
    const u16* hbase = HabsT + ((size_t)(bh * 64 + ks * 32)) * 4096 + p0 + rbase;

    int srow = t >> 2, scc = (t & 3) * 16;
    // preload tile 0 into buffer 0
    {
        int j0 = ks * 2048;
        const u32x4* gk = (const u32x4*)(kg + ((size_t)(bh * 4096 + j0 + srow)) * 64 + scc);
        u32x4* sk = (u32x4*)(Kt[0] + srow * 72 + scc);
        sk[0] = gk[0];
        sk[1] = gk[1];
        const u32x4* gv = (const u32x4*)(vt + ((size_t)(bh * 64 + srow)) * 4096 + j0 + scc);
        u32x4* sv = (u32x4*)(Vl[0] + srow * 72 + scc);
        sv[0] = gv[0];
        sv[1] = gv[1];
    }
    u16 hc0 = hbase[li];
    u16 hc1 = hbase[16 + li];

    f32x4 oacc[2][5];
#pragma unroll
    for (int rs = 0; rs < 2; ++rs)
#pragma unroll
        for (int ct = 0; ct < 5; ++ct) oacc[rs][ct] = (f32x4){0.f, 0.f, 0.f, 0.f};

    const s16x4 ones = {(short)0x3F80, (short)0x3F80, (short)0x3F80, (short)0x3F80};

    u32x4 kreg[2], vreg[2];
    u16 hn0, hn1;
    for (int kt = 0; kt < 32; ++kt) {
        __syncthreads();  // tile kt ready in buf[kt&1]; prior reads of buf[kt^1] done
        int cur = kt & 1;
        const u16* Kc = Kt[cur];
        const u16* Vc = Vl[cur];
        if (kt < 31) {
            int j0 = (ks * 32 + kt + 1) * 64;
            const u32x4* gk = (const u32x4*)(kg + ((size_t)(bh * 4096 + j0 + srow)) * 64 + scc);
            kreg[0] = gk[0];
            kreg[1] = gk[1];
            const u32x4* gv = (const u32x4*)(vt + ((size_t)(bh * 64 + srow)) * 4096 + j0 + scc);
            vreg[0] = gv[0];
            vreg[1] = gv[1];
            hn0 = hbase[(size_t)(kt + 1) * 4096 + li];
            hn1 = hbase[(size_t)(kt + 1) * 4096 + 16 + li];
        }

        // S^T = K · Q^T with bias-initialized accumulators
        float hh0 = bf2f(hc0);
        float hh1 = bf2f(hc1);
        f32x4 s[2][4];
#pragma unroll
        for (int ct = 0; ct < 4; ++ct) {
            s[0][ct] = wb4[0][ct] + hh0;
            s[1][ct] = wb4[1][ct] + hh1;
        }
#pragma unroll
        for (int kc = 0; kc < 2; ++kc) {
            bf16x8 b0 = bc8(aq[0][kc]), b1 = bc8(aq[1][kc]);
#pragma unroll
            for (int ct = 0; ct < 4; ++ct) {
                bf16x8 af = bc8(*(const u32x4*)(Kc + (ct * 16 + li) * 72 + kc * 32 + quad * 8));
                s[0][ct] = MFMA16(af, b0, s[0][ct]);
                s[1][ct] = MFMA16(af, b1, s[1][ct]);
            }
        }

        // exp2 + packed bf16 P-fragments (registers only)
        s16x4 pf[2][4];
#pragma unroll
        for (int rs = 0; rs < 2; ++rs)
#pragma unroll
            for (int ct = 0; ct < 4; ++ct) {
                u32x2 pp;
                pp.x = pack2(EXP2F(s[rs][ct][0]), EXP2F(s[rs][ct][1]));
                pp.y = pack2(EXP2F(s[rs][ct][2]), EXP2F(s[rs][ct][3]));
                pf[rs][ct] = __builtin_bit_cast(s16x4, pp);
            }

        // O += P · V ; dt=4 accumulates row sums via ones operand
#pragma unroll
        for (int jt = 0; jt < 4; ++jt) {
            s16x4 a0 = pf[0][jt], a1 = pf[1][jt];
#pragma unroll
            for (int dt = 0; dt < 4; ++dt) {
                s16x4 bv = __builtin_bit_cast(
                    s16x4, *(const u32x2*)(Vc + (dt * 16 + li) * 72 + jt * 16 + quad * 4));
                oacc[0][dt] = MFMA1K(a0, bv, oacc[0][dt]);
                oacc[1][dt] = MFMA1K(a1, bv, oacc[1][dt]);
            }
            oacc[0][4] = MFMA1K(a0, ones, oacc[0][4]);
            oacc[1][4] = MFMA1K(a1, ones, oacc[1][4]);
        }

        // commit prefetched tile to the other buffer
        if (kt < 31) {
            u32x4* sk = (u32x4*)(Kt[cur ^ 1] + srow * 72 + scc);
            sk[0] = kreg[0];
            sk[1] = kreg[1];
            u32x4* sv = (u32x4*)(Vl[cur ^ 1] + srow * 72 + scc);
            sv[0] = vreg[0];
            sv[1] = vreg[1];
            hc0 = hn0;
            hc1 = hn1;
        }
    }

    // store bf16 partials + fp32 row-sums (normalization in k_out2)
#pragma unroll
    for (int rs = 0; rs < 2; ++rs) {
#pragma unroll
        for (int ct = 0; ct < 4; ++ct)
#pragma unroll
            for (int r = 0; r < 4; ++r) {
                int p = p0 + rbase + rs * 16 + quad * 4 + r;
                OP[((size_t)((ks * 8 + bh) * 4096 + p)) * 64 + ct * 16 + li] =
                    f2bf(oacc[rs][ct][r]);
            }
        if (li == 0) {
#pragma unroll
            for (int r = 0; r < 4; ++r) {
                int p = p0 + rbase + rs * 16 + quad * 4 + r;
                LS[(size_t)(ks * 8 + bh) * 4096 + p] = oacc[rs][4][r];
            }
        }
    }
}

// ---------------------------------------------------------------------------
// K4: fused combine (2 K-slices) + out-projection + residual. grid (64 pm, 2 b, 2 coh).
__global__ __launch_bounds__(256) void k_out2(const u16* __restrict__ wob,
                                              const u16* __restrict__ OP,
                                              const float* __restrict__ LS,
                                              const float* __restrict__ x,
                                              float* __restrict__ out) {
    int pm = blockIdx.x, b = blockIdx.y, coh = blockIdx.z;
    int p0 = pm * 64;
    __shared__ __align__(16) u16 Bt[64 * 264];
    int t = threadIdx.x, wv = t >> 6, l = t & 63, quad = l >> 4, li = l & 15;

    {
        int row = t >> 2, head = t & 3;
        int bh = b * 4 + head;
        int p = p0 + row;
        const u32x4* o0p = (const u32x4*)(OP + ((size_t)(bh * 4096 + p)) * 64);
        const u32x4* o1p = (const u32x4*)(OP + ((size_t)((8 + bh) * 4096 + p)) * 64);
        float linv = 1.0f / (LS[(size_t)bh * 4096 + p] + LS[(size_t)(8 + bh) * 4096 + p]);
        u16* dst = Bt + row * 264 + head * 64;
#pragma unroll
        for (int kk = 0; kk < 8; ++kk) {
            u32x4 a = o0p[kk], c = o1p[kk];
            u32x4 pk;
            pk.x = pack2((bflo(a.x) + bflo(c.x)) * linv, (bfhi(a.x) + bfhi(c.x)) * linv);
            pk.y = pack2((bflo(a.y) + bflo(c.y)) * linv, (bfhi(a.y) + bfhi(c.y)) * linv);
            pk.z = pack2((bflo(a.z) + bflo(c.z)) * linv, (bfhi(a.z) + bfhi(c.z)) * linv);
            pk.w = pack2((bflo(a.w) + bflo(c.w)) * linv, (bfhi(a.w) + bfhi(c.w)) * linv);
            *(u32x4*)(dst + kk * 8) = pk;
        }
    }
    __syncthreads();

#pragma unroll
    for (int ci = 0; ci < 2; ++ci) {
        int com = coh * 2 + ci;
        int co0 = com * 64;
        f32x4 acc[4] = {{0, 0, 0, 0}, {0, 0, 0, 0}, {0, 0, 0, 0}, {0, 0, 0, 0}};
        const u32x4* arow = (const u32x4*)(wob + (size_t)(co0 + wv * 16 + li) * 256);
#pragma unroll
        for (int kc = 0; kc < 8; ++kc) {
            bf16x8 a = bc8(arow[kc * 4 + quad]);
#pragma unroll
            for (int ct = 0; ct < 4; ++ct) {
                bf16x8 bb = bc8(*(const u32x4*)(Bt + (ct * 16 + li) * 264 + kc * 32 + quad * 8));
                acc[ct] = MFMA16(a, bb, acc[ct]);
            }
        }
#pragma unroll
        for (int ct = 0; ct < 4; ++ct)
#pragma unroll
            for (int r = 0; r < 4; ++r) {
                size_t idx =
                    ((size_t)(b * 256 + co0 + wv * 16 + quad * 4 + r)) * 4096 + p0 + ct * 16 + li;
                out[idx] = acc[ct][r] + x[idx];
            }
    }
}

// ---------------------------------------------------------------------------
extern "C" void kernel_launch(void* const* d_in, const int* in_sizes, int n_in, void* d_out,
                              int out_size, void* d_ws, size_t ws_size, hipStream_t stream) {
    const float* x = (const float*)d_in[0];
    const float* wqkv = (const float*)d_in[1];
    const float* wout = (const float*)d_in[2];
    const float* relh = (const float*)d_in[3];
    const float* relw = (const float*)d_in[4];
    float* out = (float*)d_out;
    char* ws = (char*)d_ws;

    u16* xt = (u16*)(ws + 0);               // 4,194,304 (dead after k_qkv)
    u16* wqb = (u16*)(ws + 4194304);        //   393,216
    u16* wob = (u16*)(ws + 4587520);        //   131,072
    u16* relwb = (u16*)(ws + 4718592);      //    16,384
    u16* relhb = (u16*)(ws + 4734976);      //    16,384
    u16* qb = (u16*)(ws + 4751360);         // 4,194,304
    u16* kb = (u16*)(ws + 8945664);         // 4,194,304
    u16* vtb = (u16*)(ws + 13139968);       // 4,194,304
    u16* Wabs = (u16*)(ws + 17334272);      // 4,194,304
    u16* HabsT = (u16*)(ws + 21528576);     // 4,194,304
    u16* OPart = (u16*)(ws + 25722880);     // 8,388,608 (2 x 8 x 4096 x 64 bf16)
    float* LSum = (float*)(ws + 0);         //   262,144 (aliases dead xt)

    k_prep<<<768, 256, 0, stream>>>(x, wqkv, wout, relh, relw, xt, wqb, wob, relhb, relwb);
    k_qkv<<<dim3(64, 12, 2), 256, 0, stream>>>(xt, wqb, relwb, relhb, qb, kb, vtb, Wabs, HabsT);
    k_flash<<<dim3(32, 8, 2), 256, 0, stream>>>(qb, kb, vtb, Wabs, HabsT, OPart, LSum);
    k_out2<<<dim3(64, 2, 2), 256, 0, stream>>>(wob, OPart, LSum, x, out);
}

// Round 12
// 147.157 us; speedup vs baseline: 1.1552x; 1.0112x over previous
//
#include <hip/hip_runtime.h>

typedef unsigned short u16;
typedef unsigned int u32;
typedef __bf16 bf16x8 __attribute__((ext_vector_type(8)));
typedef __bf16 bf16x2 __attribute__((ext_vector_type(2)));
typedef float f32x4 __attribute__((ext_vector_type(4)));
typedef float f32x2 __attribute__((ext_vector_type(2)));
typedef u32 u32x4 __attribute__((ext_vector_type(4)));
typedef u32 u32x2 __attribute__((ext_vector_type(2)));
typedef short s16x4 __attribute__((ext_vector_type(4)));

#define DEVI __device__ __forceinline__

#if defined(__has_builtin)
#if __has_builtin(__builtin_amdgcn_exp2f)
#define EXP2F(x) __builtin_amdgcn_exp2f(x)
#endif
#endif
#ifndef EXP2F
#define EXP2F(x) exp2f(x)
#endif

#define MFMA16(a, b, c) __builtin_amdgcn_mfma_f32_16x16x32_bf16(a, b, c, 0, 0, 0)
#define MFMA1K(a, b, c) __builtin_amdgcn_mfma_f32_16x16x16bf16_1k(a, b, c, 0, 0, 0)

typedef __attribute__((address_space(1))) u32 gu32;
typedef __attribute__((address_space(3))) u32 lu32;
DEVI void gll16(const u16* g, u16* l) {
    __builtin_amdgcn_global_load_lds((const gu32*)g, (lu32*)l, 16, 0, 0);
}
#define WAIT_VM0() __builtin_amdgcn_s_waitcnt(0x0f70)  // vmcnt(0) only

DEVI u16 f2bf(float f) {
    u32 u = __builtin_bit_cast(u32, f);
    u = (u + 0x7FFFu + ((u >> 16) & 1u)) >> 16;
    return (u16)u;
}
DEVI float bf2f(u16 h) {
    u32 u = ((u32)h) << 16;
    return __builtin_bit_cast(float, u);
}
DEVI float bfhi(u32 u) { return __builtin_bit_cast(float, u & 0xFFFF0000u); }
DEVI float bflo(u32 u) { return __builtin_bit_cast(float, u << 16); }
DEVI bf16x8 bc8(u32x4 u) { return __builtin_bit_cast(bf16x8, u); }
DEVI s16x4 bc4(u32 a, u32 b) {
    u32x2 v = {a, b};
    return __builtin_bit_cast(s16x4, v);
}
DEVI u32 pack2(float a, float b) {
    f32x2 v = {a, b};
    bf16x2 h = __builtin_convertvector(v, bf16x2);
    return __builtin_bit_cast(u32, h);
}

// q scale: dh^-0.5 * log2(e)  (bakes natural-exp into exp2)
#define QSCALE 0.18033688011112042f

// ---------------------------------------------------------------------------
// K0: fused prep, vectorized. Blocks [0,512): transpose+cast x -> xt[b][p][c].
//     float4 global loads; packed u32x4 bf16 stores. Blocks [512,768): weights.
__global__ __launch_bounds__(256) void k_prep(const float* __restrict__ x,
                                              const float* __restrict__ wq,
                                              const float* __restrict__ wo,
                                              const float* __restrict__ relh,
                                              const float* __restrict__ relw,
                                              u16* __restrict__ xt, u16* __restrict__ wqb,
                                              u16* __restrict__ wob, u16* __restrict__ relhb,
                                              u16* __restrict__ relwb) {
    int bid = blockIdx.x;
    int t = threadIdx.x;
    if (bid < 512) {
        int pm = bid & 63, cm = (bid >> 6) & 3, b = bid >> 8;
        int p0 = pm * 64, c0 = cm * 64;
        __shared__ float tile[64][65];
#pragma unroll
        for (int it = 0; it < 4; ++it) {
            int idx = it * 256 + t;
            int cl = idx >> 4, f4 = idx & 15;
            f32x4 v = *(const f32x4*)(x + ((size_t)(b * 256 + c0 + cl)) * 4096 + p0 + f4 * 4);
            tile[cl][f4 * 4 + 0] = v[0];
            tile[cl][f4 * 4 + 1] = v[1];
            tile[cl][f4 * 4 + 2] = v[2];
            tile[cl][f4 * 4 + 3] = v[3];
        }
        __syncthreads();
#pragma unroll
        for (int it = 0; it < 2; ++it) {
            int idx = it * 256 + t;
            int pl = idx >> 3, g = idx & 7;
            u32x4 pk;
            pk.x = pack2(tile[g * 8 + 0][pl], tile[g * 8 + 1][pl]);
            pk.y = pack2(tile[g * 8 + 2][pl], tile[g * 8 + 3][pl]);
            pk.z = pack2(tile[g * 8 + 4][pl], tile[g * 8 + 5][pl]);
            pk.w = pack2(tile[g * 8 + 6][pl], tile[g * 8 + 7][pl]);
            *(u32x4*)(xt + ((size_t)(b * 4096 + p0 + pl)) * 256 + c0 + g * 8) = pk;
        }
    } else {
        int i0 = (bid - 512) * 256 + t;  // 65536 stride
#pragma unroll
        for (int i = i0; i < 196608; i += 65536) wqb[i] = f2bf(wq[i]);
        if (i0 < 65536) wob[i0] = f2bf(wo[i0]);
        if (i0 < 8192) {
            relhb[i0] = (i0 < 8128) ? f2bf(relh[i0]) : (u16)0;
            relwb[i0] = (i0 < 8128) ? f2bf(relw[i0]) : (u16)0;
        }
    }
}

// ---------------------------------------------------------------------------
// K1: QKV projection GEMM + fused rel-bias tables (B-tile staged via gll, mod-32 swizzle).
// Height table stored TRANSPOSED: HabsT[bh][jh][p].
__global__ __launch_bounds__(256) void k_qkv(const u16* __restrict__ xt, const u16* __restrict__ wqb,
                                             const u16* __restrict__ relwb,
                                             const u16* __restrict__ relhb,
                                             u16* __restrict__ q, u16* __restrict__ k,
                                             u16* __restrict__ vt, u16* __restrict__ Wabs,
                                             u16* __restrict__ HabsT) {
    int pm = blockIdx.x, on = blockIdx.y, b = blockIdx.z;
    int p0 = pm * 64, o0 = on * 64;
    __shared__ __align__(16) u16 Sm[64 * 256];  // 32 KB B-tile; later T[64*72]+Ls[128*72]
    int t = threadIdx.x;
    int wv = t >> 6, l = t & 63, quad = l >> 4, li = l & 15;

    u32x4 areg[8];
    const u32x4* arow = (const u32x4*)(xt + ((size_t)(b * 4096 + p0 + wv * 16 + li)) * 256);
#pragma unroll
    for (int kc = 0; kc < 8; ++kc) areg[kc] = arow[kc * 4 + quad];

    {
        int pc = l & 31;
#pragma unroll
        for (int i = 0; i < 8; ++i) {
            int r = wv * 16 + i * 2 + (l >> 5);
            gll16(wqb + (size_t)(o0 + r) * 256 + ((pc + r) & 31) * 8,
                  Sm + (wv * 16 + i * 2) * 256);
        }
    }
    WAIT_VM0();
    __syncthreads();

    f32x4 acc[4] = {{0, 0, 0, 0}, {0, 0, 0, 0}, {0, 0, 0, 0}, {0, 0, 0, 0}};
#pragma unroll
    for (int kc = 0; kc < 8; ++kc) {
        bf16x8 a = bc8(areg[kc]);
#pragma unroll
        for (int ct = 0; ct < 4; ++ct) {
            bf16x8 bb = bc8(*(const u32x4*)(Sm + (ct * 16 + li) * 256 +
                                            (((kc * 4 + quad) - (ct * 16 + li)) & 31) * 8));
            acc[ct] = MFMA16(a, bb, acc[ct]);
        }
    }

    int tensor = on >> 2, head = on & 3;
    if (tensor == 2) {
        __syncthreads();
        u16* T = Sm;  // [64 d][72 p]
#pragma unroll
        for (int ct = 0; ct < 4; ++ct)
#pragma unroll
            for (int r = 0; r < 4; ++r)
                T[(ct * 16 + li) * 72 + wv * 16 + quad * 4 + r] = f2bf(acc[ct][r]);
        __syncthreads();
        int dr = t >> 2, pc = (t & 3) * 16;
        u32x4* g = (u32x4*)(vt + ((size_t)((b * 4 + head) * 64 + dr)) * 4096 + p0 + pc);
        const u32x4* s2 = (const u32x4*)(T + dr * 72 + pc);
        g[0] = s2[0];
        g[1] = s2[1];
    } else {
        u16* outp = (tensor == 0) ? q : k;
        float sc = (tensor == 0) ? QSCALE : 1.0f;
#pragma unroll
        for (int ct = 0; ct < 4; ++ct)
#pragma unroll
            for (int r = 0; r < 4; ++r) {
                int p = p0 + wv * 16 + quad * 4 + r;
                int d = ct * 16 + li;
                outp[((size_t)((b * 4 + head) * 4096 + p)) * 64 + d] = f2bf(acc[ct][r] * sc);
            }
        if (tensor == 0) {
            // ---- fused rel-bias tables ----
            int bh = b * 4 + head;
            u16* T = Sm;             // [64 p][72 d]
            u16* Ls = Sm + 64 * 72;  // [128 r][72 d]
            __syncthreads();  // all GEMM Sm reads done
#pragma unroll
            for (int ct = 0; ct < 4; ++ct)
#pragma unroll
                for (int r = 0; r < 4; ++r)
                    T[(wv * 16 + quad * 4 + r) * 72 + ct * 16 + li] = f2bf(acc[ct][r] * QSCALE);
            {
                int row = t >> 1, half = t & 1;
                const u32x4* g2 = (const u32x4*)(relwb + row * 64 + half * 32);
                u32x4* s2 = (u32x4*)(Ls + row * 72 + half * 32);
#pragma unroll
                for (int kk = 0; kk < 4; ++kk) s2[kk] = g2[kk];
            }
            __syncthreads();
            u32x4 aq2[2];
            aq2[0] = *(const u32x4*)(T + (wv * 16 + li) * 72 + quad * 8);
            aq2[1] = *(const u32x4*)(T + (wv * 16 + li) * 72 + 32 + quad * 8);

            f32x4 acc2[8];
#pragma unroll
            for (int ct = 0; ct < 8; ++ct) acc2[ct] = (f32x4){0.f, 0.f, 0.f, 0.f};
#pragma unroll
            for (int kc = 0; kc < 2; ++kc) {
                bf16x8 a = bc8(aq2[kc]);
#pragma unroll
                for (int ct = 0; ct < 8; ++ct) {
                    bf16x8 bb = bc8(*(const u32x4*)(Ls + (ct * 16 + li) * 72 + kc * 32 + quad * 8));
                    acc2[ct] = MFMA16(a, bb, acc2[ct]);
                }
            }
#pragma unroll
            for (int ct = 0; ct < 8; ++ct)
#pragma unroll
                for (int r = 0; r < 4; ++r) {
                    int row = wv * 16 + quad * 4 + r;
                    int j = (ct * 16 + li) - 63 + row;  // shift = y = row
                    if (j >= 0 && j < 64)
                        Wabs[((size_t)(bh * 4096 + p0 + row)) * 64 + j] = f2bf(acc2[ct][r]);
                }
            __syncthreads();  // Ls reads done
            {
                int row = t >> 1, half = t & 1;
                const u32x4* g2 = (const u32x4*)(relhb + row * 64 + half * 32);
                u32x4* s2 = (u32x4*)(Ls + row * 72 + half * 32);
#pragma unroll
                for (int kk = 0; kk < 4; ++kk) s2[kk] = g2[kk];
            }
            __syncthreads();
#pragma unroll
            for (int ct = 0; ct < 8; ++ct) acc2[ct] = (f32x4){0.f, 0.f, 0.f, 0.f};
#pragma unroll
            for (int kc = 0; kc < 2; ++kc) {
                bf16x8 a = bc8(aq2[kc]);
#pragma unroll
                for (int ct = 0; ct < 8; ++ct) {
                    bf16x8 bb = bc8(*(const u32x4*)(Ls + (ct * 16 + li) * 72 + kc * 32 + quad * 8));
                    acc2[ct] = MFMA16(a, bb, acc2[ct]);
                }
            }
            // store TRANSPOSED: HabsT[bh][jh][p]
#pragma unroll
            for (int ct = 0; ct < 8; ++ct)
#pragma unroll
                for (int r = 0; r < 4; ++r) {
                    int row = wv * 16 + quad * 4 + r;
                    int j = (ct * 16 + li) - 63 + pm;  // shift = x = pm
                    if (j >= 0 && j < 64)
                        HabsT[((size_t)(bh * 64 + j)) * 4096 + p0 + row] = f2bf(acc2[ct][r]);
                }
        }
    }
}

// ---------------------------------------------------------------------------
// K3: flash attention v11. K-split x2, 36.9 KB LDS, launch_bounds (256,2).
// V LDS tile stored with j-field swap (j' = quad*16 + jt*4 + r) so each lane's
// four jt B-frags are 16 consecutive u16 -> 2 ds_read_b128 per dt (8/iter)
// instead of 16 ds_read_b64 (DS-pipe is the measured bottleneck, R10/R11).
__global__ __launch_bounds__(256, 2) void k_flash(const u16* __restrict__ q,
                                                  const u16* __restrict__ kg,
                                                  const u16* __restrict__ vt,
                                                  const u16* __restrict__ Wabs,
                                                  const u16* __restrict__ HabsT,
                                                  u16* __restrict__ OP,
                                                  float* __restrict__ LS) {
    int pm = blockIdx.x, bh = blockIdx.y, ks = blockIdx.z;
    int p0 = pm * 128;
    __shared__ __align__(16) u16 Kt[2][64 * 72];
    __shared__ __align__(16) u16 Vl[2][64 * 72];
    int t = threadIdx.x, wv = t >> 6, l = t & 63, quad = l >> 4, li = l & 15;
    int rbase = wv * 32;

    // Q B-frags for both row-sets
    u32x4 aq[2][2];
#pragma unroll
    for (int rs = 0; rs < 2; ++rs) {
        const u32x4* qrow =
            (const u32x4*)(q + ((size_t)(bh * 4096 + p0 + rbase + rs * 16 + li)) * 64);
        aq[rs][0] = qrow[quad];
        aq[rs][1] = qrow[4 + quad];
    }

    // width-bias as f32x4 per (rs,ct), aligned to the S^T C-frag
    f32x4 wb4[2][4];
#pragma unroll
    for (int rs = 0; rs < 2; ++rs)
#pragma unroll
        for (int ct = 0; ct < 4; ++ct) {
            const u32* wp = (const u32*)(Wabs +
                                         ((size_t)(bh * 4096 + p0 + rbase + rs * 16 + li)) * 64 +
                                         ct * 16 + quad * 4);
            u32 lo = wp[0], hi = wp[1];
            wb4[rs][ct] = (f32x4){bflo(lo), bfhi(lo), bflo(hi), bfhi(hi)};
        }

    // height-bias source: HabsT[bh][jh][p]; per iter rows rbase+li, rbase+16+li
    const u16* hbase = HabsT + ((size_t)(bh * 64 + ks * 32)) * 4096 + p0 + rbase;

    int srow = t >> 2, scc = (t & 3) * 16, jt4 = (t & 3) * 4;
    // preload tile 0 into buffer 0
    {
        int j0 = ks * 2048;
        const u32x4* gk = (const u32x4*)(kg + ((size_t)(bh * 4096 + j0 + srow)) * 64 + scc);
        u32x4* sk = (u32x4*)(Kt[0] + srow * 72 + scc);
        sk[0] = gk[0];
        sk[1] = gk[1];
        const u32x4* gv = (const u32x4*)(vt + ((size_t)(bh * 64 + srow)) * 4096 + j0 + scc);
        u32x4 v0 = gv[0], v1 = gv[1];
        u16* vr = Vl[0] + srow * 72;
        *(u32x2*)(vr + jt4) = (u32x2){v0.x, v0.y};
        *(u32x2*)(vr + 16 + jt4) = (u32x2){v0.z, v0.w};
        *(u32x2*)(vr + 32 + jt4) = (u32x2){v1.x, v1.y};
        *(u32x2*)(vr + 48 + jt4) = (u32x2){v1.z, v1.w};
    }
    u16 hc0 = hbase[li];
    u16 hc1 = hbase[16 + li];

    f32x4 oacc[2][5];
#pragma unroll
    for (int rs = 0; rs < 2; ++rs)
#pragma unroll
        for (int ct = 0; ct < 5; ++ct) oacc[rs][ct] = (f32x4){0.f, 0.f, 0.f, 0.f};

    const s16x4 ones = {(short)0x3F80, (short)0x3F80, (short)0x3F80, (short)0x3F80};

    u32x4 kreg[2], vreg[2];
    u16 hn0, hn1;
    for (int kt = 0; kt < 32; ++kt) {
        __syncthreads();  // tile kt ready in buf[kt&1]; prior reads of buf[kt^1] done
        int cur = kt & 1;
        const u16* Kc = Kt[cur];
        const u16* Vc = Vl[cur];
        if (kt < 31) {
            int j0 = (ks * 32 + kt + 1) * 64;
            const u32x4* gk = (const u32x4*)(kg + ((size_t)(bh * 4096 + j0 + srow)) * 64 + scc);
            kreg[0] = gk[0];
            kreg[1] = gk[1];
            const u32x4* gv = (const u32x4*)(vt + ((size_t)(bh * 64 + srow)) * 4096 + j0 + scc);
            vreg[0] = gv[0];
            vreg[1] = gv[1];
            hn0 = hbase[(size_t)(kt + 1) * 4096 + li];
            hn1 = hbase[(size_t)(kt + 1) * 4096 + 16 + li];
        }

        // S^T = K · Q^T with bias-initialized accumulators
        float hh0 = bf2f(hc0);
        float hh1 = bf2f(hc1);
        f32x4 s[2][4];
#pragma unroll
        for (int ct = 0; ct < 4; ++ct) {
            s[0][ct] = wb4[0][ct] + hh0;
            s[1][ct] = wb4[1][ct] + hh1;
        }
#pragma unroll
        for (int kc = 0; kc < 2; ++kc) {
            bf16x8 b0 = bc8(aq[0][kc]), b1 = bc8(aq[1][kc]);
#pragma unroll
            for (int ct = 0; ct < 4; ++ct) {
                bf16x8 af = bc8(*(const u32x4*)(Kc + (ct * 16 + li) * 72 + kc * 32 + quad * 8));
                s[0][ct] = MFMA16(af, b0, s[0][ct]);
                s[1][ct] = MFMA16(af, b1, s[1][ct]);
            }
        }

        // exp2 + packed bf16 P-fragments (registers only)
        s16x4 pf[2][4];
#pragma unroll
        for (int rs = 0; rs < 2; ++rs)
#pragma unroll
            for (int ct = 0; ct < 4; ++ct) {
                u32x2 pp;
                pp.x = pack2(EXP2F(s[rs][ct][0]), EXP2F(s[rs][ct][1]));
                pp.y = pack2(EXP2F(s[rs][ct][2]), EXP2F(s[rs][ct][3]));
                pf[rs][ct] = __builtin_bit_cast(s16x4, pp);
            }

        // O += P · V : per dt, 2 b128 reads deliver all four jt B-frags
#pragma unroll
        for (int dt = 0; dt < 4; ++dt) {
            const u16* vr = Vc + (dt * 16 + li) * 72 + quad * 16;
            u32x4 B0 = *(const u32x4*)(vr);
            u32x4 B1 = *(const u32x4*)(vr + 8);
            s16x4 bv0 = bc4(B0.x, B0.y), bv1 = bc4(B0.z, B0.w);
            s16x4 bv2 = bc4(B1.x, B1.y), bv3 = bc4(B1.z, B1.w);
            oacc[0][dt] = MFMA1K(pf[0][0], bv0, oacc[0][dt]);
            oacc[1][dt] = MFMA1K(pf[1][0], bv0, oacc[1][dt]);
            oacc[0][dt] = MFMA1K(pf[0][1], bv1, oacc[0][dt]);
            oacc[1][dt] = MFMA1K(pf[1][1], bv1, oacc[1][dt]);
            oacc[0][dt] = MFMA1K(pf[0][2], bv2, oacc[0][dt]);
            oacc[1][dt] = MFMA1K(pf[1][2], bv2, oacc[1][dt]);
            oacc[0][dt] = MFMA1K(pf[0][3], bv3, oacc[0][dt]);
            oacc[1][dt] = MFMA1K(pf[1][3], bv3, oacc[1][dt]);
        }
        // row sums via ones operand
#pragma unroll
        for (int jt = 0; jt < 4; ++jt) {
            oacc[0][4] = MFMA1K(pf[0][jt], ones, oacc[0][4]);
            oacc[1][4] = MFMA1K(pf[1][jt], ones, oacc[1][4]);
        }

        // commit prefetched tile to the other buffer
        if (kt < 31) {
            u32x4* sk = (u32x4*)(Kt[cur ^ 1] + srow * 72 + scc);
            sk[0] = kreg[0];
            sk[1] = kreg[1];
            u16* vr = Vl[cur ^ 1] + srow * 72;
            *(u32x2*)(vr + jt4) = (u32x2){vreg[0].x, vreg[0].y};
            *(u32x2*)(vr + 16 + jt4) = (u32x2){vreg[0].z, vreg[0].w};
            *(u32x2*)(vr + 32 + jt4) = (u32x2){vreg[1].x, vreg[1].y};
            *(u32x2*)(vr + 48 + jt4) = (u32x2){vreg[1].z, vreg[1].w};
            hc0 = hn0;
            hc1 = hn1;
        }
    }

    // store bf16 partials + fp32 row-sums (normalization in k_out2)
#pragma unroll
    for (int rs = 0; rs < 2; ++rs) {
#pragma unroll
        for (int ct = 0; ct < 4; ++ct)
#pragma unroll
            for (int r = 0; r < 4; ++r) {
                int p = p0 + rbase + rs * 16 + quad * 4 + r;
                OP[((size_t)((ks * 8 + bh) * 4096 + p)) * 64 + ct * 16 + li] =
                    f2bf(oacc[rs][ct][r]);
            }
        if (li == 0) {
#pragma unroll
            for (int r = 0; r < 4; ++r) {
                int p = p0 + rbase + rs * 16 + quad * 4 + r;
                LS[(size_t)(ks * 8 + bh) * 4096 + p] = oacc[rs][4][r];
            }
        }
    }
}

// ---------------------------------------------------------------------------
// K4: fused combine (2 K-slices) + out-projection + residual. grid (64 pm, 2 b, 2 coh).
__global__ __launch_bounds__(256) void k_out2(const u16* __restrict__ wob,
                                              const u16* __restrict__ OP,
                                              const float* __restrict__ LS,
                                              const float* __restrict__ x,
                                              float* __restrict__ out) {
    int pm = blockIdx.x, b = blockIdx.y, coh = blockIdx.z;
    int p0 = pm * 64;
    __shared__ __align__(16) u16 Bt[64 * 264];
    int t = threadIdx.x, wv = t >> 6, l = t & 63, quad = l >> 4, li = l & 15;

    {
        int row = t >> 2, head = t & 3;
        int bh = b * 4 + head;
        int p = p0 + row;
        const u32x4* o0p = (const u32x4*)(OP + ((size_t)(bh * 4096 + p)) * 64);
        const u32x4* o1p = (const u32x4*)(OP + ((size_t)((8 + bh) * 4096 + p)) * 64);
        float linv = 1.0f / (LS[(size_t)bh * 4096 + p] + LS[(size_t)(8 + bh) * 4096 + p]);
        u16* dst = Bt + row * 264 + head * 64;
#pragma unroll
        for (int kk = 0; kk < 8; ++kk) {
            u32x4 a = o0p[kk], c = o1p[kk];
            u32x4 pk;
            pk.x = pack2((bflo(a.x) + bflo(c.x)) * linv, (bfhi(a.x) + bfhi(c.x)) * linv);
            pk.y = pack2((bflo(a.y) + bflo(c.y)) * linv, (bfhi(a.y) + bfhi(c.y)) * linv);
            pk.z = pack2((bflo(a.z) + bflo(c.z)) * linv, (bfhi(a.z) + bfhi(c.z)) * linv);
            pk.w = pack2((bflo(a.w) + bflo(c.w)) * linv, (bfhi(a.w) + bfhi(c.w)) * linv);
            *(u32x4*)(dst + kk * 8) = pk;
        }
    }
    __syncthreads();

#pragma unroll
    for (int ci = 0; ci < 2; ++ci) {
        int com = coh * 2 + ci;
        int co0 = com * 64;
        f32x4 acc[4] = {{0, 0, 0, 0}, {0, 0, 0, 0}, {0, 0, 0, 0}, {0, 0, 0, 0}};
        const u32x4* arow = (const u32x4*)(wob + (size_t)(co0 + wv * 16 + li) * 256);
#pragma unroll
        for (int kc = 0; kc < 8; ++kc) {
            bf16x8 a = bc8(arow[kc * 4 + quad]);
#pragma unroll
            for (int ct = 0; ct < 4; ++ct) {
                bf16x8 bb = bc8(*(const u32x4*)(Bt + (ct * 16 + li) * 264 + kc * 32 + quad * 8));
                acc[ct] = MFMA16(a, bb, acc[ct]);
            }
        }
#pragma unroll
        for (int ct = 0; ct < 4; ++ct)
#pragma unroll
            for (int r = 0; r < 4; ++r) {
                size_t idx =
                    ((size_t)(b * 256 + co0 + wv * 16 + quad * 4 + r)) * 4096 + p0 + ct * 16 + li;
                out[idx] = acc[ct][r] + x[idx];
            }
    }
}

// ---------------------------------------------------------------------------
extern "C" void kernel_launch(void* const* d_in, const int* in_sizes, int n_in, void* d_out,
                              int out_size, void* d_ws, size_t ws_size, hipStream_t stream) {
    const float* x = (const float*)d_in[0];
    const float* wqkv = (const float*)d_in[1];
    const float* wout = (const float*)d_in[2];
    const float* relh = (const float*)d_in[3];
    const float* relw = (const float*)d_in[4];
    float* out = (float*)d_out;
    char* ws = (char*)d_ws;

    u16* xt = (u16*)(ws + 0);               // 4,194,304 (dead after k_qkv)
    u16* wqb = (u16*)(ws + 4194304);        //   393,216
    u16* wob = (u16*)(ws + 4587520);        //   131,072
    u16* relwb = (u16*)(ws + 4718592);      //    16,384
    u16* relhb = (u16*)(ws + 4734976);      //    16,384
    u16* qb = (u16*)(ws + 4751360);         // 4,194,304
    u16* kb = (u16*)(ws + 8945664);         // 4,194,304
    u16* vtb = (u16*)(ws + 13139968);       // 4,194,304
    u16* Wabs = (u16*)(ws + 17334272);      // 4,194,304
    u16* HabsT = (u16*)(ws + 21528576);     // 4,194,304
    u16* OPart = (u16*)(ws + 25722880);     // 8,388,608 (2 x 8 x 4096 x 64 bf16)
    float* LSum = (float*)(ws + 0);         //   262,144 (aliases dead xt)

    k_prep<<<768, 256, 0, stream>>>(x, wqkv, wout, relh, relw, xt, wqb, wob, relhb, relwb);
    k_qkv<<<dim3(64, 12, 2), 256, 0, stream>>>(xt, wqb, relwb, relhb, qb, kb, vtb, Wabs, HabsT);
    k_flash<<<dim3(32, 8, 2), 256, 0, stream>>>(qb, kb, vtb, Wabs, HabsT, OPart, LSum);
    k_out2<<<dim3(64, 2, 2), 256, 0, stream>>>(wob, OPart, LSum, x, out);
}